// Round 1
// baseline (797.507 us; speedup 1.0000x reference)
//
#include <hip/hip_runtime.h>
#include <hip/hip_bf16.h>

#define DM 1024
#define NHEADS 16
#define DKH 64
#define BATCH 4
#define SEQ 2048
#define MROWS (BATCH*SEQ)   // 8192

typedef __attribute__((ext_vector_type(8))) short bf16x8;
typedef __attribute__((ext_vector_type(4))) short bf16x4;
typedef __attribute__((ext_vector_type(4))) float f32x4;

__device__ __forceinline__ unsigned short f2bf(float f){
  unsigned u = __float_as_uint(f);
  u += 0x7fffu + ((u >> 16) & 1u);   // RNE
  return (unsigned short)(u >> 16);
}

// ---------------- fp32 -> bf16 conversion ----------------
__global__ __launch_bounds__(256) void conv_f32_bf16(const float* __restrict__ in,
                                                     unsigned short* __restrict__ out, int n){
  int i = (blockIdx.x * blockDim.x + threadIdx.x) * 4;
  if (i < n){
    const float4 v = *reinterpret_cast<const float4*>(in + i);
    ushort4 o;
    o.x = f2bf(v.x); o.y = f2bf(v.y); o.z = f2bf(v.z); o.w = f2bf(v.w);
    *reinterpret_cast<ushort4*>(out + i) = o;
  }
}

// ---------------- GEMM: C[m,n] = sum_k A[m,k]*W[n,k] + bias[n] ----------------
// A: [M,K] bf16 row-major, W: [N,K] bf16 row-major (torch Linear weight).
// MODE 0: bf16 out in [B,H,S,DKH] layout, scaled by `scale` (for Q; K uses scale=1)
// MODE 1: bf16 out in [B,H,DKH,S] layout (V transposed)
// MODE 2: f32 out row-major [M,N] (final projection)
template<int MODE>
__global__ __launch_bounds__(256)
void gemm_bt(const unsigned short* __restrict__ A, const unsigned short* __restrict__ Bw,
             const float* __restrict__ bias, void* __restrict__ out, float scale)
{
  const int K = 1024;
  __shared__ short a_sh[128*64];
  __shared__ short b_sh[128*64];
  const int tid  = threadIdx.x;
  const int lane = tid & 63;
  const int wid  = tid >> 6;
  const int wm = wid >> 1, wn = wid & 1;           // 2x2 waves -> 64x64 each
  const int tileM = blockIdx.x * 128;
  const int tileN = blockIdx.y * 128;

  f32x4 acc[4][4];
  #pragma unroll
  for (int i = 0; i < 4; i++)
    #pragma unroll
    for (int j = 0; j < 4; j++)
      acc[i][j] = (f32x4){0.f,0.f,0.f,0.f};

  const int lr = lane & 15;
  const int lg = lane >> 4;

  for (int k0 = 0; k0 < K; k0 += 64){
    bf16x8 ra[4], rb[4];
    #pragma unroll
    for (int i = 0; i < 4; i++){
      int v   = tid + 256*i;        // 0..1023
      int row = v >> 3;             // 0..127
      int cg  = v & 7;              // 8-bf16 column group
      ra[i] = *reinterpret_cast<const bf16x8*>(A  + (size_t)(tileM+row)*K + k0 + cg*8);
      rb[i] = *reinterpret_cast<const bf16x8*>(Bw + (size_t)(tileN+row)*K + k0 + cg*8);
    }
    __syncthreads();
    #pragma unroll
    for (int i = 0; i < 4; i++){
      int v   = tid + 256*i;
      int row = v >> 3;
      int cg  = v & 7;
      *reinterpret_cast<bf16x8*>(&a_sh[row*64 + ((cg ^ (row & 7)) * 8)]) = ra[i];
      *reinterpret_cast<bf16x8*>(&b_sh[row*64 + ((cg ^ (row & 7)) * 8)]) = rb[i];
    }
    __syncthreads();
    #pragma unroll
    for (int kk = 0; kk < 64; kk += 32){
      bf16x8 af[4], bfr[4];
      const int g0 = lg + (kk >> 3);
      #pragma unroll
      for (int fm = 0; fm < 4; fm++){
        int row = wm*64 + fm*16 + lr;
        af[fm] = *reinterpret_cast<const bf16x8*>(&a_sh[row*64 + ((g0 ^ (row & 7)) * 8)]);
      }
      #pragma unroll
      for (int fn = 0; fn < 4; fn++){
        int row = wn*64 + fn*16 + lr;
        bfr[fn] = *reinterpret_cast<const bf16x8*>(&b_sh[row*64 + ((g0 ^ (row & 7)) * 8)]);
      }
      #pragma unroll
      for (int fm = 0; fm < 4; fm++)
        #pragma unroll
        for (int fn = 0; fn < 4; fn++)
          acc[fm][fn] = __builtin_amdgcn_mfma_f32_16x16x32_bf16(af[fm], bfr[fn], acc[fm][fn], 0, 0, 0);
    }
  }

  // epilogue: C layout col = lane&15, row = (lane>>4)*4 + reg
  #pragma unroll
  for (int fm = 0; fm < 4; fm++){
    #pragma unroll
    for (int fn = 0; fn < 4; fn++){
      #pragma unroll
      for (int r = 0; r < 4; r++){
        int m = tileM + wm*64 + fm*16 + lg*4 + r;
        int n = tileN + wn*64 + fn*16 + lr;
        float val = acc[fm][fn][r] + bias[n];
        if (MODE == 0){
          val *= scale;
          int b = m >> 11, s = m & 2047, h = n >> 6, d = n & 63;
          ((unsigned short*)out)[(((size_t)(b*NHEADS + h)*SEQ + s)*DKH + d)] = f2bf(val);
        } else if (MODE == 1){
          int b = m >> 11, s = m & 2047, h = n >> 6, d = n & 63;
          ((unsigned short*)out)[(((size_t)(b*NHEADS + h)*DKH + d)*SEQ + s)] = f2bf(val);
        } else {
          ((float*)out)[(size_t)m*DM + n] = val;
        }
      }
    }
  }
}

// ---------------- flash attention (causal) ----------------
// Q,K: [B,H,S,DKH] bf16 (Q pre-scaled by 1/8). Vt: [B,H,DKH,S] bf16.
// Out: [B,S,DM] bf16 (attention output, pre output-projection).
__global__ __launch_bounds__(256)
void attn_kernel(const unsigned short* __restrict__ Q, const unsigned short* __restrict__ Kb,
                 const unsigned short* __restrict__ Vt, unsigned short* __restrict__ Oout)
{
  const int lane = threadIdx.x & 63;
  const int wid  = threadIdx.x >> 6;
  const int qt   = blockIdx.x * 4 + wid;     // 0..127  (16-row q tile)
  const int bh   = blockIdx.y;               // 0..63
  const int b = bh >> 4, h = bh & 15;

  const size_t base  = (size_t)bh * SEQ * DKH;
  const size_t vbase = (size_t)bh * DKH * SEQ;
  const int qcol = lane & 15;     // q (column of S^T tile)
  const int grp  = lane >> 4;     // lane group

  bf16x8 qf0, qf1;
  {
    size_t off = base + (size_t)(qt*16 + qcol)*DKH + grp*8;
    qf0 = *reinterpret_cast<const bf16x8*>(Q + off);
    qf1 = *reinterpret_cast<const bf16x8*>(Q + off + 32);
  }

  float mrun = -__builtin_inff();
  float lrun = 0.f;
  f32x4 o[4];
  #pragma unroll
  for (int dc = 0; dc < 4; dc++) o[dc] = (f32x4){0.f,0.f,0.f,0.f};

  for (int kt = 0; kt <= qt; kt++){
    size_t koff = base + (size_t)(kt*16 + qcol)*DKH + grp*8;
    bf16x8 kf0 = *reinterpret_cast<const bf16x8*>(Kb + koff);
    bf16x8 kf1 = *reinterpret_cast<const bf16x8*>(Kb + koff + 32);
    // S^T tile: rows = k (16), cols = q (16); accumulate over d=64
    f32x4 st = (f32x4){0.f,0.f,0.f,0.f};
    st = __builtin_amdgcn_mfma_f32_16x16x32_bf16(kf0, qf0, st, 0, 0, 0);
    st = __builtin_amdgcn_mfma_f32_16x16x32_bf16(kf1, qf1, st, 0, 0, 0);

    if (kt == qt){
      #pragma unroll
      for (int r = 0; r < 4; r++){
        int kl = grp*4 + r;
        if (kl > qcol) st[r] = -__builtin_inff();
      }
    }
    // per-q (column) online softmax
    float mt = fmaxf(fmaxf(st[0], st[1]), fmaxf(st[2], st[3]));
    mt = fmaxf(mt, __shfl_xor(mt, 16));
    mt = fmaxf(mt, __shfl_xor(mt, 32));
    float mnew = fmaxf(mrun, mt);
    float corr = __expf(mrun - mnew);
    float p0 = __expf(st[0] - mnew);
    float p1 = __expf(st[1] - mnew);
    float p2 = __expf(st[2] - mnew);
    float p3 = __expf(st[3] - mnew);
    float ps = p0 + p1 + p2 + p3;
    ps += __shfl_xor(ps, 16);
    ps += __shfl_xor(ps, 32);
    lrun = lrun * corr + ps;
    mrun = mnew;

    bf16x4 pb;
    pb[0] = (short)f2bf(p0); pb[1] = (short)f2bf(p1);
    pb[2] = (short)f2bf(p2); pb[3] = (short)f2bf(p3);

    #pragma unroll
    for (int dc = 0; dc < 4; dc++){
      o[dc][0] *= corr; o[dc][1] *= corr; o[dc][2] *= corr; o[dc][3] *= corr;
      size_t voff = vbase + (size_t)(dc*16 + qcol)*SEQ + kt*16 + grp*4;
      bf16x4 vf = *reinterpret_cast<const bf16x4*>(Vt + voff);
      o[dc] = __builtin_amdgcn_mfma_f32_16x16x16bf16_1k(vf, pb, o[dc], 0, 0, 0);
    }
  }

  float inv = 1.0f / lrun;
  int s = qt*16 + qcol;
  #pragma unroll
  for (int dc = 0; dc < 4; dc++){
    #pragma unroll
    for (int r = 0; r < 4; r++){
      int d = dc*16 + grp*4 + r;
      Oout[(size_t)(b*SEQ + s)*DM + h*DKH + d] = f2bf(o[dc][r] * inv);
    }
  }
}

extern "C" void kernel_launch(void* const* d_in, const int* in_sizes, int n_in,
                              void* d_out, int out_size, void* d_ws, size_t ws_size,
                              hipStream_t stream) {
  const float* query = (const float*)d_in[0];
  const float* key   = (const float*)d_in[1];
  const float* value = (const float*)d_in[2];
  // d_in[3] = causal mask (tril ones) — implemented analytically
  const float* Wq = (const float*)d_in[4];
  const float* bq = (const float*)d_in[5];
  const float* Wk = (const float*)d_in[6];
  const float* bk = (const float*)d_in[7];
  const float* Wv = (const float*)d_in[8];
  const float* bv = (const float*)d_in[9];
  const float* Wo = (const float*)d_in[10];
  const float* bo = (const float*)d_in[11];
  float* out = (float*)d_out;

  char* ws = (char*)d_ws;
  const size_t SZ_X = (size_t)MROWS * DM * 2;   // 16 MB
  const size_t SZ_W = (size_t)DM * DM * 2;      // 2 MB
  unsigned short* qb  = (unsigned short*)(ws + 0);
  unsigned short* kb  = (unsigned short*)(ws + SZ_X);
  unsigned short* vb  = (unsigned short*)(ws + 2*SZ_X);
  unsigned short* wqb = (unsigned short*)(ws + 3*SZ_X);
  unsigned short* wkb = (unsigned short*)(ws + 3*SZ_X + SZ_W);
  unsigned short* wvb = (unsigned short*)(ws + 3*SZ_X + 2*SZ_W);
  unsigned short* wob = (unsigned short*)(ws + 3*SZ_X + 3*SZ_W);
  unsigned short* Vt  = (unsigned short*)(ws + 3*SZ_X + 4*SZ_W);  // 16 MB
  // Aliases (strictly sequential stream, producers precede consumers):
  unsigned short* Qb   = vb;   // written after vb consumed by V-GEMM
  unsigned short* Kbuf = qb;   // written after qb consumed by Q-GEMM
  unsigned short* attO = kb;   // written after kb consumed by K-GEMM

  const int nX = MROWS * DM;   // 8388608
  const int nW = DM * DM;      // 1048576
  conv_f32_bf16<<<nX/1024, 256, 0, stream>>>(query, qb, nX);
  conv_f32_bf16<<<nX/1024, 256, 0, stream>>>(key,   kb, nX);
  conv_f32_bf16<<<nX/1024, 256, 0, stream>>>(value, vb, nX);
  conv_f32_bf16<<<nW/1024, 256, 0, stream>>>(Wq, wqb, nW);
  conv_f32_bf16<<<nW/1024, 256, 0, stream>>>(Wk, wkb, nW);
  conv_f32_bf16<<<nW/1024, 256, 0, stream>>>(Wv, wvb, nW);
  conv_f32_bf16<<<nW/1024, 256, 0, stream>>>(Wo, wob, nW);

  dim3 gg(MROWS/128, DM/128);   // (64, 8)
  gemm_bt<1><<<gg, 256, 0, stream>>>(vb, wvb, bv, (void*)Vt,   1.0f);
  gemm_bt<0><<<gg, 256, 0, stream>>>(qb, wqb, bq, (void*)Qb,   0.125f);  // 1/sqrt(64)
  gemm_bt<0><<<gg, 256, 0, stream>>>(kb, wkb, bk, (void*)Kbuf, 1.0f);

  attn_kernel<<<dim3(SEQ/16/4, BATCH*NHEADS), 256, 0, stream>>>(Qb, Kbuf, Vt, attO);

  gemm_bt<2><<<gg, 256, 0, stream>>>(attO, wob, bo, (void*)out, 1.0f);
}

// Round 2
// 221.130 us; speedup vs baseline: 3.6065x; 3.6065x over previous
//
#include <hip/hip_runtime.h>
#include <hip/hip_bf16.h>

#define DM 1024
#define NHEADS 16
#define DKH 64
#define BATCH 4
#define SEQ 2048
#define MROWS (BATCH*SEQ)   // 8192

typedef __attribute__((ext_vector_type(8))) short bf16x8;
typedef __attribute__((ext_vector_type(4))) short bf16x4;
typedef __attribute__((ext_vector_type(4))) float f32x4;

__device__ __forceinline__ unsigned short f2bf(float f){
  unsigned u = __float_as_uint(f);
  u += 0x7fffu + ((u >> 16) & 1u);   // RNE
  return (unsigned short)(u >> 16);
}

__device__ __forceinline__ void gload16(const unsigned short* g, unsigned short* l){
  __builtin_amdgcn_global_load_lds((const __attribute__((address_space(1))) void*)g,
                                   (__attribute__((address_space(3))) void*)l, 16, 0, 0);
}

// ---------------- fp32 -> bf16 conversion ----------------
__global__ __launch_bounds__(256) void conv_f32_bf16(const float* __restrict__ in,
                                                     unsigned short* __restrict__ out, int n){
  int i = (blockIdx.x * blockDim.x + threadIdx.x) * 4;
  if (i < n){
    const float4 v = *reinterpret_cast<const float4*>(in + i);
    ushort4 o;
    o.x = f2bf(v.x); o.y = f2bf(v.y); o.z = f2bf(v.z); o.w = f2bf(v.w);
    *reinterpret_cast<ushort4*>(out + i) = o;
  }
}

// ---------------- GEMM: C[m,n] = sum_k A[m,k]*W[n,k] + bias[n] ----------------
template<int MODE>
__global__ __launch_bounds__(256)
void gemm_bt(const unsigned short* __restrict__ A, const unsigned short* __restrict__ Bw,
             const float* __restrict__ bias, void* __restrict__ out, float scale)
{
  const int K = 1024;
  __shared__ short a_sh[128*64];
  __shared__ short b_sh[128*64];
  const int tid  = threadIdx.x;
  const int lane = tid & 63;
  const int wid  = tid >> 6;
  const int wm = wid >> 1, wn = wid & 1;           // 2x2 waves -> 64x64 each
  const int tileM = blockIdx.x * 128;
  const int tileN = blockIdx.y * 128;

  f32x4 acc[4][4];
  #pragma unroll
  for (int i = 0; i < 4; i++)
    #pragma unroll
    for (int j = 0; j < 4; j++)
      acc[i][j] = (f32x4){0.f,0.f,0.f,0.f};

  const int lr = lane & 15;
  const int lg = lane >> 4;

  for (int k0 = 0; k0 < K; k0 += 64){
    bf16x8 ra[4], rb[4];
    #pragma unroll
    for (int i = 0; i < 4; i++){
      int v   = tid + 256*i;        // 0..1023
      int row = v >> 3;             // 0..127
      int cg  = v & 7;              // 8-bf16 column group
      ra[i] = *reinterpret_cast<const bf16x8*>(A  + (size_t)(tileM+row)*K + k0 + cg*8);
      rb[i] = *reinterpret_cast<const bf16x8*>(Bw + (size_t)(tileN+row)*K + k0 + cg*8);
    }
    __syncthreads();
    #pragma unroll
    for (int i = 0; i < 4; i++){
      int v   = tid + 256*i;
      int row = v >> 3;
      int cg  = v & 7;
      *reinterpret_cast<bf16x8*>(&a_sh[row*64 + ((cg ^ (row & 7)) * 8)]) = ra[i];
      *reinterpret_cast<bf16x8*>(&b_sh[row*64 + ((cg ^ (row & 7)) * 8)]) = rb[i];
    }
    __syncthreads();
    #pragma unroll
    for (int kk = 0; kk < 64; kk += 32){
      bf16x8 af[4], bfr[4];
      const int g0 = lg + (kk >> 3);
      #pragma unroll
      for (int fm = 0; fm < 4; fm++){
        int row = wm*64 + fm*16 + lr;
        af[fm] = *reinterpret_cast<const bf16x8*>(&a_sh[row*64 + ((g0 ^ (row & 7)) * 8)]);
      }
      #pragma unroll
      for (int fn = 0; fn < 4; fn++){
        int row = wn*64 + fn*16 + lr;
        bfr[fn] = *reinterpret_cast<const bf16x8*>(&b_sh[row*64 + ((g0 ^ (row & 7)) * 8)]);
      }
      #pragma unroll
      for (int fm = 0; fm < 4; fm++)
        #pragma unroll
        for (int fn = 0; fn < 4; fn++)
          acc[fm][fn] = __builtin_amdgcn_mfma_f32_16x16x32_bf16(af[fm], bfr[fn], acc[fm][fn], 0, 0, 0);
    }
  }

  #pragma unroll
  for (int fm = 0; fm < 4; fm++){
    #pragma unroll
    for (int fn = 0; fn < 4; fn++){
      #pragma unroll
      for (int r = 0; r < 4; r++){
        int m = tileM + wm*64 + fm*16 + lg*4 + r;
        int n = tileN + wn*64 + fn*16 + lr;
        float val = acc[fm][fn][r] + bias[n];
        if (MODE == 0){
          val *= scale;
          int b = m >> 11, s = m & 2047, h = n >> 6, d = n & 63;
          ((unsigned short*)out)[(((size_t)(b*NHEADS + h)*SEQ + s)*DKH + d)] = f2bf(val);
        } else if (MODE == 1){
          int b = m >> 11, s = m & 2047, h = n >> 6, d = n & 63;
          ((unsigned short*)out)[(((size_t)(b*NHEADS + h)*DKH + d)*SEQ + s)] = f2bf(val);
        } else {
          ((float*)out)[(size_t)m*DM + n] = val;
        }
      }
    }
  }
}

// ---------------- flash attention (causal), LDS-staged, 128 q-rows/block ----------------
// Q,K: [B,H,S,DKH] bf16 (Q pre-scaled). Vt: [B,H,DKH,S] bf16. Out: [B,S,DM] bf16.
__global__ __launch_bounds__(256)
void attn_kernel(const unsigned short* __restrict__ Q, const unsigned short* __restrict__ Kb,
                 const unsigned short* __restrict__ Vt, unsigned short* __restrict__ Oout)
{
  __shared__ unsigned short k_sh[2][64*64];   // [kblock row][d], XOR-swizzled 16B groups
  __shared__ unsigned short v_sh[2][64*64];   // [d][kblock col], XOR-swizzled 16B groups
  const int lane = threadIdx.x & 63;
  const int w    = threadIdx.x >> 6;
  const int lr = lane & 15, grp = lane >> 4;
  const int bh = blockIdx.x;                  // 0..63
  const int qtile = 15 - (int)blockIdx.y;     // heavy-first dispatch
  const int qb0 = qtile * 128;
  const int qw0 = qb0 + w * 32;               // wave's first q row
  const int b = bh >> 4, h = bh & 15;
  const size_t kbase = (size_t)bh * SEQ * DKH;
  const size_t vbase = (size_t)bh * DKH * SEQ;

  // ---- staging source offsets (pre-swizzled so linear LDS == swizzled layout) ----
  const int r8 = lane >> 3, c8 = lane & 7;
  const int rowS0 = w*16 + r8;        // rows this lane stages, call 0
  const int rowS1 = w*16 + 8 + r8;    // call 1
  const size_t offK0 = (size_t)rowS0*DKH  + (size_t)((c8 ^ (rowS0 & 7)) * 8);
  const size_t offK1 = (size_t)rowS1*DKH  + (size_t)((c8 ^ (rowS1 & 7)) * 8);
  const size_t offV0 = (size_t)rowS0*SEQ  + (size_t)((c8 ^ (rowS0 & 7)) * 8);
  const size_t offV1 = (size_t)rowS1*SEQ  + (size_t)((c8 ^ (rowS1 & 7)) * 8);
  const int ldsA = (w*16)*64;
  const int ldsB = (w*16+8)*64;

  // ---- Q fragments (held in registers for the whole kernel) ----
  bf16x8 qf[2][2];
  #pragma unroll
  for (int qg = 0; qg < 2; qg++){
    size_t off = kbase + (size_t)(qw0 + qg*16 + lr)*DKH + grp*8;
    qf[qg][0] = *reinterpret_cast<const bf16x8*>(Q + off);
    qf[qg][1] = *reinterpret_cast<const bf16x8*>(Q + off + 32);
  }

  float mrun[2] = {-__builtin_inff(), -__builtin_inff()};
  float lrun[2] = {0.f, 0.f};
  f32x4 o[2][4];
  #pragma unroll
  for (int qg = 0; qg < 2; qg++)
    #pragma unroll
    for (int dc = 0; dc < 4; dc++) o[qg][dc] = (f32x4){0.f,0.f,0.f,0.f};

  const int nkb = qb0/64 + 2;

#define STAGE(kb_, bf_) do { \
    gload16(Kb + kbase + (size_t)(kb_)*4096 + offK0, (unsigned short*)&k_sh[bf_][ldsA]); \
    gload16(Kb + kbase + (size_t)(kb_)*4096 + offK1, (unsigned short*)&k_sh[bf_][ldsB]); \
    gload16(Vt + vbase + (size_t)(kb_)*64   + offV0, (unsigned short*)&v_sh[bf_][ldsA]); \
    gload16(Vt + vbase + (size_t)(kb_)*64   + offV1, (unsigned short*)&v_sh[bf_][ldsB]); \
  } while(0)

  STAGE(0, 0);
  __syncthreads();

  for (int kb = 0; kb < nkb; kb++){
    const int buf = kb & 1;
    if (kb + 1 < nkb) STAGE(kb + 1, buf ^ 1);

    if (kb*64 <= qw0 + 31){   // wave has any live rows for this k block
      const unsigned short* ks = k_sh[buf];
      const unsigned short* vs = v_sh[buf];
      const bool act0 = (kb*64 <= qw0 + 15);   // lower q group live?

      // ---- QK^T: S^T tiles [k=16][q=16] per (qg, ksub) ----
      f32x4 st[2][4];
      #pragma unroll
      for (int ksub = 0; ksub < 4; ksub++){
        int rowk = ksub*16 + lr;
        bf16x8 kf0 = *reinterpret_cast<const bf16x8*>(&ks[rowk*64 + ((grp ^ (rowk & 7)) * 8)]);
        bf16x8 kf1 = *reinterpret_cast<const bf16x8*>(&ks[rowk*64 + (((4 + grp) ^ (rowk & 7)) * 8)]);
        #pragma unroll
        for (int qg = 0; qg < 2; qg++){
          f32x4 s = (f32x4){0.f,0.f,0.f,0.f};
          s = __builtin_amdgcn_mfma_f32_16x16x32_bf16(kf0, qf[qg][0], s, 0, 0, 0);
          s = __builtin_amdgcn_mfma_f32_16x16x32_bf16(kf1, qf[qg][1], s, 0, 0, 0);
          st[qg][ksub] = s;
        }
      }

      // ---- online softmax per q group over the 64-k block ----
      bf16x4 pb[2][4];
      #pragma unroll
      for (int qg = 0; qg < 2; qg++){
        if (qg == 0 && !act0) continue;
        const int qgb = qw0 + qg*16;         // group q base; lane q = qgb + lr
        if (kb*64 + 63 > qgb){               // diagonal: apply causal mask
          #pragma unroll
          for (int ksub = 0; ksub < 4; ksub++)
            #pragma unroll
            for (int r = 0; r < 4; r++){
              int kg = kb*64 + ksub*16 + grp*4 + r;
              if (kg > qgb + lr) st[qg][ksub][r] = -__builtin_inff();
            }
        }
        float mt = st[qg][0][0];
        #pragma unroll
        for (int ksub = 0; ksub < 4; ksub++)
          #pragma unroll
          for (int r = 0; r < 4; r++) mt = fmaxf(mt, st[qg][ksub][r]);
        mt = fmaxf(mt, __shfl_xor(mt, 16));
        mt = fmaxf(mt, __shfl_xor(mt, 32));
        float mnew = fmaxf(mrun[qg], mt);
        float corr = __expf(mrun[qg] - mnew);
        float ps = 0.f;
        #pragma unroll
        for (int ksub = 0; ksub < 4; ksub++){
          #pragma unroll
          for (int r = 0; r < 4; r++){
            float p = __expf(st[qg][ksub][r] - mnew);
            ps += p;
            pb[qg][ksub][r] = (short)f2bf(p);
          }
        }
        ps += __shfl_xor(ps, 16);
        ps += __shfl_xor(ps, 32);
        lrun[qg] = lrun[qg]*corr + ps;
        mrun[qg] = mnew;
        #pragma unroll
        for (int dc = 0; dc < 4; dc++){
          o[qg][dc][0] *= corr; o[qg][dc][1] *= corr;
          o[qg][dc][2] *= corr; o[qg][dc][3] *= corr;
        }
      }

      // ---- PV: O[d][q] += V^T[d][k] * P^T[k][q] ----
      #pragma unroll
      for (int ksub = 0; ksub < 4; ksub++){
        #pragma unroll
        for (int dc = 0; dc < 4; dc++){
          int rowd = dc*16 + lr;
          int cg16 = ksub*2 + (grp >> 1);
          bf16x4 vf = *reinterpret_cast<const bf16x4*>(
              &vs[rowd*64 + ((cg16 ^ (rowd & 7)) * 8) + (grp & 1)*4]);
          if (act0) o[0][dc] = __builtin_amdgcn_mfma_f32_16x16x16bf16_1k(vf, pb[0][ksub], o[0][dc], 0, 0, 0);
          o[1][dc] = __builtin_amdgcn_mfma_f32_16x16x16bf16_1k(vf, pb[1][ksub], o[1][dc], 0, 0, 0);
        }
      }
    }
    __syncthreads();
  }
#undef STAGE

  // ---- epilogue ----
  #pragma unroll
  for (int qg = 0; qg < 2; qg++){
    float inv = 1.0f / lrun[qg];
    int qglob = qw0 + qg*16 + lr;
    size_t ob = ((size_t)(b*SEQ + qglob))*DM + h*DKH;
    #pragma unroll
    for (int dc = 0; dc < 4; dc++){
      ushort4 pk;
      pk.x = f2bf(o[qg][dc][0]*inv);
      pk.y = f2bf(o[qg][dc][1]*inv);
      pk.z = f2bf(o[qg][dc][2]*inv);
      pk.w = f2bf(o[qg][dc][3]*inv);
      *reinterpret_cast<ushort4*>(&Oout[ob + dc*16 + grp*4]) = pk;
    }
  }
}

extern "C" void kernel_launch(void* const* d_in, const int* in_sizes, int n_in,
                              void* d_out, int out_size, void* d_ws, size_t ws_size,
                              hipStream_t stream) {
  const float* query = (const float*)d_in[0];
  const float* key   = (const float*)d_in[1];
  const float* value = (const float*)d_in[2];
  const float* Wq = (const float*)d_in[4];
  const float* bq = (const float*)d_in[5];
  const float* Wk = (const float*)d_in[6];
  const float* bk = (const float*)d_in[7];
  const float* Wv = (const float*)d_in[8];
  const float* bv = (const float*)d_in[9];
  const float* Wo = (const float*)d_in[10];
  const float* bo = (const float*)d_in[11];
  float* out = (float*)d_out;

  char* ws = (char*)d_ws;
  const size_t SZ_X = (size_t)MROWS * DM * 2;   // 16 MB
  const size_t SZ_W = (size_t)DM * DM * 2;      // 2 MB
  unsigned short* qb  = (unsigned short*)(ws + 0);
  unsigned short* kb  = (unsigned short*)(ws + SZ_X);
  unsigned short* vb  = (unsigned short*)(ws + 2*SZ_X);
  unsigned short* wqb = (unsigned short*)(ws + 3*SZ_X);
  unsigned short* wkb = (unsigned short*)(ws + 3*SZ_X + SZ_W);
  unsigned short* wvb = (unsigned short*)(ws + 3*SZ_X + 2*SZ_W);
  unsigned short* wob = (unsigned short*)(ws + 3*SZ_X + 3*SZ_W);
  unsigned short* Vt  = (unsigned short*)(ws + 3*SZ_X + 4*SZ_W);  // 16 MB
  unsigned short* Qb   = vb;   // aliases: strictly sequential producer->consumer
  unsigned short* Kbuf = qb;
  unsigned short* attO = kb;

  const int nX = MROWS * DM;
  const int nW = DM * DM;
  conv_f32_bf16<<<nX/1024, 256, 0, stream>>>(query, qb, nX);
  conv_f32_bf16<<<nX/1024, 256, 0, stream>>>(key,   kb, nX);
  conv_f32_bf16<<<nX/1024, 256, 0, stream>>>(value, vb, nX);
  conv_f32_bf16<<<nW/1024, 256, 0, stream>>>(Wq, wqb, nW);
  conv_f32_bf16<<<nW/1024, 256, 0, stream>>>(Wk, wkb, nW);
  conv_f32_bf16<<<nW/1024, 256, 0, stream>>>(Wv, wvb, nW);
  conv_f32_bf16<<<nW/1024, 256, 0, stream>>>(Wo, wob, nW);

  dim3 gg(MROWS/128, DM/128);   // (64, 8)
  gemm_bt<1><<<gg, 256, 0, stream>>>(vb, wvb, bv, (void*)Vt,   1.0f);
  gemm_bt<0><<<gg, 256, 0, stream>>>(qb, wqb, bq, (void*)Qb,   0.125f);  // 1/sqrt(64)
  gemm_bt<0><<<gg, 256, 0, stream>>>(kb, wkb, bk, (void*)Kbuf, 1.0f);

  attn_kernel<<<dim3(64, 16), 256, 0, stream>>>(Qb, Kbuf, Vt, attO);

  gemm_bt<2><<<gg, 256, 0, stream>>>(attO, wob, bo, (void*)out, 1.0f);
}

// Round 4
// 216.604 us; speedup vs baseline: 3.6819x; 1.0209x over previous
//
#include <hip/hip_runtime.h>
#include <hip/hip_bf16.h>

#define DM 1024
#define NHEADS 16
#define DKH 64
#define BATCH 4
#define SEQ 2048
#define MROWS (BATCH*SEQ)   // 8192

typedef __attribute__((ext_vector_type(8))) short bf16x8;
typedef __attribute__((ext_vector_type(4))) short bf16x4;
typedef __attribute__((ext_vector_type(4))) float f32x4;

#if __has_builtin(__builtin_amdgcn_exp2f)
#define EXP2(x) __builtin_amdgcn_exp2f(x)
#else
#define EXP2(x) exp2f(x)
#endif

__device__ __forceinline__ unsigned short f2bf(float f){
  unsigned u = __float_as_uint(f);
  u += 0x7fffu + ((u >> 16) & 1u);   // RNE
  return (unsigned short)(u >> 16);
}

__device__ __forceinline__ void gload16(const unsigned short* g, unsigned short* l){
  __builtin_amdgcn_global_load_lds((const __attribute__((address_space(1))) void*)g,
                                   (__attribute__((address_space(3))) void*)l, 16, 0, 0);
}

// ---------------- fused fp32 -> bf16 conversion (all 7 tensors, 1 dispatch) ----------------
struct ConvArgs { const float* src[7]; unsigned short* dst[7]; };

__global__ __launch_bounds__(256) void conv_all(ConvArgs a){
  const int bx = blockIdx.x;
  int t, boff;
  if (bx < 24576){ t = bx >> 13; boff = bx & 8191; }          // q,k,v: 8192 blocks each
  else { int j = bx - 24576; t = 3 + (j >> 10); boff = j & 1023; }  // 4 weights: 1024 each
  const float* __restrict__ src = a.src[t];
  unsigned short* __restrict__ dst = a.dst[t];
  const int i = (boff * 256 + threadIdx.x) * 4;
  const float4 v = *reinterpret_cast<const float4*>(src + i);
  ushort4 o;
  o.x = f2bf(v.x); o.y = f2bf(v.y); o.z = f2bf(v.z); o.w = f2bf(v.w);
  *reinterpret_cast<ushort4*>(dst + i) = o;
}

// ---------------- GEMM: C[m,n] = sum_k A[m,k]*W[n,k] + bias[n] ----------------
template<int MODE>
__global__ __launch_bounds__(256)
void gemm_bt(const unsigned short* __restrict__ A, const unsigned short* __restrict__ Bw,
             const float* __restrict__ bias, void* __restrict__ out, float scale)
{
  const int K = 1024;
  __shared__ short a_sh[128*64];
  __shared__ short b_sh[128*64];
  const int tid  = threadIdx.x;
  const int lane = tid & 63;
  const int wid  = tid >> 6;
  const int wm = wid >> 1, wn = wid & 1;           // 2x2 waves -> 64x64 each
  const int tileM = blockIdx.x * 128;
  const int tileN = blockIdx.y * 128;

  f32x4 acc[4][4];
  #pragma unroll
  for (int i = 0; i < 4; i++)
    #pragma unroll
    for (int j = 0; j < 4; j++)
      acc[i][j] = (f32x4){0.f,0.f,0.f,0.f};

  const int lr = lane & 15;
  const int lg = lane >> 4;

  for (int k0 = 0; k0 < K; k0 += 64){
    bf16x8 ra[4], rb[4];
    #pragma unroll
    for (int i = 0; i < 4; i++){
      int v   = tid + 256*i;        // 0..1023
      int row = v >> 3;             // 0..127
      int cg  = v & 7;              // 8-bf16 column group
      ra[i] = *reinterpret_cast<const bf16x8*>(A  + (size_t)(tileM+row)*K + k0 + cg*8);
      rb[i] = *reinterpret_cast<const bf16x8*>(Bw + (size_t)(tileN+row)*K + k0 + cg*8);
    }
    __syncthreads();
    #pragma unroll
    for (int i = 0; i < 4; i++){
      int v   = tid + 256*i;
      int row = v >> 3;
      int cg  = v & 7;
      *reinterpret_cast<bf16x8*>(&a_sh[row*64 + ((cg ^ (row & 7)) * 8)]) = ra[i];
      *reinterpret_cast<bf16x8*>(&b_sh[row*64 + ((cg ^ (row & 7)) * 8)]) = rb[i];
    }
    __syncthreads();
    #pragma unroll
    for (int kk = 0; kk < 64; kk += 32){
      bf16x8 af[4], bfr[4];
      const int g0 = lg + (kk >> 3);
      #pragma unroll
      for (int fm = 0; fm < 4; fm++){
        int row = wm*64 + fm*16 + lr;
        af[fm] = *reinterpret_cast<const bf16x8*>(&a_sh[row*64 + ((g0 ^ (row & 7)) * 8)]);
      }
      #pragma unroll
      for (int fn = 0; fn < 4; fn++){
        int row = wn*64 + fn*16 + lr;
        bfr[fn] = *reinterpret_cast<const bf16x8*>(&b_sh[row*64 + ((g0 ^ (row & 7)) * 8)]);
      }
      #pragma unroll
      for (int fm = 0; fm < 4; fm++)
        #pragma unroll
        for (int fn = 0; fn < 4; fn++)
          acc[fm][fn] = __builtin_amdgcn_mfma_f32_16x16x32_bf16(af[fm], bfr[fn], acc[fm][fn], 0, 0, 0);
    }
  }

  #pragma unroll
  for (int fm = 0; fm < 4; fm++){
    #pragma unroll
    for (int fn = 0; fn < 4; fn++){
      #pragma unroll
      for (int r = 0; r < 4; r++){
        int m = tileM + wm*64 + fm*16 + lg*4 + r;
        int n = tileN + wn*64 + fn*16 + lr;
        float val = acc[fm][fn][r] + bias[n];
        if (MODE == 0){
          val *= scale;
          int b = m >> 11, s = m & 2047, h = n >> 6, d = n & 63;
          ((unsigned short*)out)[(((size_t)(b*NHEADS + h)*SEQ + s)*DKH + d)] = f2bf(val);
        } else if (MODE == 1){
          int b = m >> 11, s = m & 2047, h = n >> 6, d = n & 63;
          ((unsigned short*)out)[(((size_t)(b*NHEADS + h)*DKH + d)*SEQ + s)] = f2bf(val);
        } else {
          ((float*)out)[(size_t)m*DM + n] = val;
        }
      }
    }
  }
}

// ---------------- flash attention (causal), LDS-staged, 128 q-rows/block ----------------
// Q,K: [B,H,S,DKH] bf16 (Q pre-scaled by log2e/sqrt(dk)). Vt: [B,H,DKH,S] bf16.
// Softmax in exp2 domain, ALWAYS-rescale (round-2 semantics). l-sum via ones-MFMA.
__global__ __launch_bounds__(256)
void attn_kernel(const unsigned short* __restrict__ Q, const unsigned short* __restrict__ Kb,
                 const unsigned short* __restrict__ Vt, unsigned short* __restrict__ Oout)
{
  __shared__ unsigned short k_sh[2][64*64];   // [k row][d], XOR-swizzled 16B groups
  __shared__ unsigned short v_sh[2][64*64];   // [d][k col], XOR-swizzled 16B groups
  const int lane = threadIdx.x & 63;
  const int w    = threadIdx.x >> 6;
  const int lr = lane & 15, grp = lane >> 4;
  const int bh = blockIdx.x;                  // 0..63
  const int qtile = 15 - (int)blockIdx.y;     // heavy-first dispatch
  const int qb0 = qtile * 128;
  const int qw0 = qb0 + w * 32;               // wave's first q row
  const int b = bh >> 4, h = bh & 15;
  const size_t kbase = (size_t)bh * SEQ * DKH;
  const size_t vbase = (size_t)bh * DKH * SEQ;

  // staging source offsets (pre-swizzled: linear LDS dest == swizzled layout)
  const int r8 = lane >> 3, c8 = lane & 7;
  const int rowS0 = w*16 + r8;
  const int rowS1 = w*16 + 8 + r8;
  const size_t offK0 = (size_t)rowS0*DKH  + (size_t)((c8 ^ (rowS0 & 7)) * 8);
  const size_t offK1 = (size_t)rowS1*DKH  + (size_t)((c8 ^ (rowS1 & 7)) * 8);
  const size_t offV0 = (size_t)rowS0*SEQ  + (size_t)((c8 ^ (rowS0 & 7)) * 8);
  const size_t offV1 = (size_t)rowS1*SEQ  + (size_t)((c8 ^ (rowS1 & 7)) * 8);
  const int ldsA = (w*16)*64;
  const int ldsB = (w*16+8)*64;

  // Q fragments (registers for whole kernel)
  bf16x8 qf[2][2];
  #pragma unroll
  for (int qg = 0; qg < 2; qg++){
    size_t off = kbase + (size_t)(qw0 + qg*16 + lr)*DKH + grp*8;
    qf[qg][0] = *reinterpret_cast<const bf16x8*>(Q + off);
    qf[qg][1] = *reinterpret_cast<const bf16x8*>(Q + off + 32);
  }

  bf16x4 ones4;
  ones4[0] = (short)0x3F80; ones4[1] = (short)0x3F80;
  ones4[2] = (short)0x3F80; ones4[3] = (short)0x3F80;

  float mrun[2] = {-__builtin_inff(), -__builtin_inff()};
  f32x4 ls[2];
  f32x4 o[2][4];
  #pragma unroll
  for (int qg = 0; qg < 2; qg++){
    ls[qg] = (f32x4){0.f,0.f,0.f,0.f};
    #pragma unroll
    for (int dc = 0; dc < 4; dc++) o[qg][dc] = (f32x4){0.f,0.f,0.f,0.f};
  }

  const int nkb = qb0/64 + 2;

#define STAGE(kb_, bf_) do { \
    gload16(Kb + kbase + (size_t)(kb_)*4096 + offK0, (unsigned short*)&k_sh[bf_][ldsA]); \
    gload16(Kb + kbase + (size_t)(kb_)*4096 + offK1, (unsigned short*)&k_sh[bf_][ldsB]); \
    gload16(Vt + vbase + (size_t)(kb_)*64   + offV0, (unsigned short*)&v_sh[bf_][ldsA]); \
    gload16(Vt + vbase + (size_t)(kb_)*64   + offV1, (unsigned short*)&v_sh[bf_][ldsB]); \
  } while(0)

  STAGE(0, 0);
  __syncthreads();

  for (int kb = 0; kb < nkb; kb++){
    const int buf = kb & 1;
    if (kb + 1 < nkb) STAGE(kb + 1, buf ^ 1);

    if (kb*64 <= qw0 + 31){
      const unsigned short* ks = k_sh[buf];
      const unsigned short* vs = v_sh[buf];
      const bool act0 = (kb*64 <= qw0 + 15);

      // ---- QK^T: S^T tiles [k=16][q=16] ----
      f32x4 st[2][4];
      __builtin_amdgcn_s_setprio(1);
      #pragma unroll
      for (int ksub = 0; ksub < 4; ksub++){
        int rowk = ksub*16 + lr;
        bf16x8 kf0 = *reinterpret_cast<const bf16x8*>(&ks[rowk*64 + ((grp ^ (rowk & 7)) * 8)]);
        bf16x8 kf1 = *reinterpret_cast<const bf16x8*>(&ks[rowk*64 + (((4 + grp) ^ (rowk & 7)) * 8)]);
        #pragma unroll
        for (int qg = 0; qg < 2; qg++){
          f32x4 s = (f32x4){0.f,0.f,0.f,0.f};
          s = __builtin_amdgcn_mfma_f32_16x16x32_bf16(kf0, qf[qg][0], s, 0, 0, 0);
          s = __builtin_amdgcn_mfma_f32_16x16x32_bf16(kf1, qf[qg][1], s, 0, 0, 0);
          st[qg][ksub] = s;
        }
      }
      __builtin_amdgcn_s_setprio(0);

      // ---- online softmax (exp2 domain, always-rescale) ----
      bf16x4 pb[2][4];
      #pragma unroll
      for (int qg = 0; qg < 2; qg++){
        if (qg == 0 && !act0) continue;
        const int qgb = qw0 + qg*16;
        if (kb*64 + 63 > qgb){   // diagonal: causal mask
          #pragma unroll
          for (int ksub = 0; ksub < 4; ksub++)
            #pragma unroll
            for (int r = 0; r < 4; r++){
              int kg = kb*64 + ksub*16 + grp*4 + r;
              if (kg > qgb + lr) st[qg][ksub][r] = -__builtin_inff();
            }
        }
        float mt = fmaxf(fmaxf(st[qg][0][0], st[qg][0][1]), fmaxf(st[qg][0][2], st[qg][0][3]));
        #pragma unroll
        for (int ksub = 1; ksub < 4; ksub++){
          mt = fmaxf(mt, fmaxf(fmaxf(st[qg][ksub][0], st[qg][ksub][1]),
                               fmaxf(st[qg][ksub][2], st[qg][ksub][3])));
        }
        mt = fmaxf(mt, __shfl_xor(mt, 16));
        mt = fmaxf(mt, __shfl_xor(mt, 32));
        const float mnew = fmaxf(mrun[qg], mt);
        const float corr = EXP2(mrun[qg] - mnew);   // exp2(-inf)=0 at first tile
        mrun[qg] = mnew;
        #pragma unroll
        for (int dc = 0; dc < 4; dc++){
          o[qg][dc][0] *= corr; o[qg][dc][1] *= corr;
          o[qg][dc][2] *= corr; o[qg][dc][3] *= corr;
        }
        ls[qg][0] *= corr;
        #pragma unroll
        for (int ksub = 0; ksub < 4; ksub++){
          float p0 = EXP2(st[qg][ksub][0] - mnew);
          float p1 = EXP2(st[qg][ksub][1] - mnew);
          float p2 = EXP2(st[qg][ksub][2] - mnew);
          float p3 = EXP2(st[qg][ksub][3] - mnew);
          pb[qg][ksub][0] = (short)f2bf(p0);
          pb[qg][ksub][1] = (short)f2bf(p1);
          pb[qg][ksub][2] = (short)f2bf(p2);
          pb[qg][ksub][3] = (short)f2bf(p3);
        }
      }

      // ---- PV + l-sum on the matrix pipe ----
      __builtin_amdgcn_s_setprio(1);
      #pragma unroll
      for (int ksub = 0; ksub < 4; ksub++){
        #pragma unroll
        for (int dc = 0; dc < 4; dc++){
          int rowd = dc*16 + lr;
          int cg16 = ksub*2 + (grp >> 1);
          bf16x4 vf = *reinterpret_cast<const bf16x4*>(
              &vs[rowd*64 + ((cg16 ^ (rowd & 7)) * 8) + (grp & 1)*4]);
          if (act0) o[0][dc] = __builtin_amdgcn_mfma_f32_16x16x16bf16_1k(vf, pb[0][ksub], o[0][dc], 0, 0, 0);
          o[1][dc] = __builtin_amdgcn_mfma_f32_16x16x16bf16_1k(vf, pb[1][ksub], o[1][dc], 0, 0, 0);
        }
        if (act0) ls[0] = __builtin_amdgcn_mfma_f32_16x16x16bf16_1k(ones4, pb[0][ksub], ls[0], 0, 0, 0);
        ls[1] = __builtin_amdgcn_mfma_f32_16x16x16bf16_1k(ones4, pb[1][ksub], ls[1], 0, 0, 0);
      }
      __builtin_amdgcn_s_setprio(0);
    }
    __syncthreads();
  }
#undef STAGE

  // ---- epilogue ----
  #pragma unroll
  for (int qg = 0; qg < 2; qg++){
    float inv = 1.0f / ls[qg][0];
    int qglob = qw0 + qg*16 + lr;
    size_t ob = ((size_t)(b*SEQ + qglob))*DM + h*DKH;
    #pragma unroll
    for (int dc = 0; dc < 4; dc++){
      ushort4 pk;
      pk.x = f2bf(o[qg][dc][0]*inv);
      pk.y = f2bf(o[qg][dc][1]*inv);
      pk.z = f2bf(o[qg][dc][2]*inv);
      pk.w = f2bf(o[qg][dc][3]*inv);
      *reinterpret_cast<ushort4*>(&Oout[ob + dc*16 + grp*4]) = pk;
    }
  }
}

extern "C" void kernel_launch(void* const* d_in, const int* in_sizes, int n_in,
                              void* d_out, int out_size, void* d_ws, size_t ws_size,
                              hipStream_t stream) {
  const float* query = (const float*)d_in[0];
  const float* key   = (const float*)d_in[1];
  const float* value = (const float*)d_in[2];
  const float* Wq = (const float*)d_in[4];
  const float* bq = (const float*)d_in[5];
  const float* Wk = (const float*)d_in[6];
  const float* bk = (const float*)d_in[7];
  const float* Wv = (const float*)d_in[8];
  const float* bv = (const float*)d_in[9];
  const float* Wo = (const float*)d_in[10];
  const float* bo = (const float*)d_in[11];
  float* out = (float*)d_out;

  char* ws = (char*)d_ws;
  const size_t SZ_X = (size_t)MROWS * DM * 2;   // 16 MB
  const size_t SZ_W = (size_t)DM * DM * 2;      // 2 MB
  unsigned short* qb  = (unsigned short*)(ws + 0);
  unsigned short* kb  = (unsigned short*)(ws + SZ_X);
  unsigned short* vb  = (unsigned short*)(ws + 2*SZ_X);
  unsigned short* wqb = (unsigned short*)(ws + 3*SZ_X);
  unsigned short* wkb = (unsigned short*)(ws + 3*SZ_X + SZ_W);
  unsigned short* wvb = (unsigned short*)(ws + 3*SZ_X + 2*SZ_W);
  unsigned short* wob = (unsigned short*)(ws + 3*SZ_X + 3*SZ_W);
  unsigned short* Vt  = (unsigned short*)(ws + 3*SZ_X + 4*SZ_W);  // 16 MB
  unsigned short* Qb   = vb;   // aliases: strictly sequential producer->consumer
  unsigned short* Kbuf = qb;
  unsigned short* attO = kb;

  ConvArgs ca;
  ca.src[0] = query; ca.src[1] = key; ca.src[2] = value;
  ca.src[3] = Wq; ca.src[4] = Wk; ca.src[5] = Wv; ca.src[6] = Wo;
  ca.dst[0] = qb; ca.dst[1] = kb; ca.dst[2] = vb;
  ca.dst[3] = wqb; ca.dst[4] = wkb; ca.dst[5] = wvb; ca.dst[6] = wob;
  conv_all<<<28672, 256, 0, stream>>>(ca);

  dim3 gg(MROWS/128, DM/128);   // (64, 8)
  const float qscale = 0.125f * 1.4426950408889634f;   // 1/sqrt(dk) * log2(e)
  gemm_bt<1><<<gg, 256, 0, stream>>>(vb, wvb, bv, (void*)Vt,   1.0f);
  gemm_bt<0><<<gg, 256, 0, stream>>>(qb, wqb, bq, (void*)Qb,   qscale);
  gemm_bt<0><<<gg, 256, 0, stream>>>(kb, wkb, bk, (void*)Kbuf, 1.0f);

  attn_kernel<<<dim3(64, 16), 256, 0, stream>>>(Qb, Kbuf, Vt, attO);

  gemm_bt<2><<<gg, 256, 0, stream>>>(attO, wob, bo, (void*)out, 1.0f);
}

// Round 5
// 200.148 us; speedup vs baseline: 3.9846x; 1.0822x over previous
//
#include <hip/hip_runtime.h>
#include <hip/hip_bf16.h>

#define DM 1024
#define NHEADS 16
#define DKH 64
#define BATCH 4
#define SEQ 2048
#define MROWS (BATCH*SEQ)   // 8192

typedef __attribute__((ext_vector_type(8))) short bf16x8;
typedef __attribute__((ext_vector_type(4))) short bf16x4;
typedef __attribute__((ext_vector_type(4))) float f32x4;

#if __has_builtin(__builtin_amdgcn_exp2f)
#define EXP2(x) __builtin_amdgcn_exp2f(x)
#else
#define EXP2(x) exp2f(x)
#endif

__device__ __forceinline__ unsigned short f2bf(float f){
  unsigned u = __float_as_uint(f);
  u += 0x7fffu + ((u >> 16) & 1u);   // RNE
  return (unsigned short)(u >> 16);
}

__device__ __forceinline__ unsigned pk2bf(float lo, float hi){
  union { __hip_bfloat162 h; unsigned u; } c;
  c.h = __float22bfloat162_rn(make_float2(lo, hi));   // v_cvt_pk_bf16_f32 (RNE)
  return c.u;
}

__device__ __forceinline__ bf16x8 cvtA8(float4 a, float4 b){
  union { unsigned u[4]; bf16x8 v; } r;
  r.u[0] = pk2bf(a.x, a.y);
  r.u[1] = pk2bf(a.z, a.w);
  r.u[2] = pk2bf(b.x, b.y);
  r.u[3] = pk2bf(b.z, b.w);
  return r.v;
}

__device__ __forceinline__ void gload16(const unsigned short* g, unsigned short* l){
  __builtin_amdgcn_global_load_lds((const __attribute__((address_space(1))) void*)g,
                                   (__attribute__((address_space(3))) void*)l, 16, 0, 0);
}

// ---------------- fp32 -> bf16 conversion (4 weight matrices only) ----------------
struct ConvArgs { const float* src[4]; unsigned short* dst[4]; };

__global__ __launch_bounds__(256) void conv_w(ConvArgs a){
  const int t = blockIdx.x >> 10;          // 4 tensors x 1024 blocks
  const int boff = blockIdx.x & 1023;
  const float* __restrict__ src = a.src[t];
  unsigned short* __restrict__ dst = a.dst[t];
  const int i = (boff * 256 + threadIdx.x) * 4;
  const float4 v = *reinterpret_cast<const float4*>(src + i);
  ushort4 o;
  o.x = f2bf(v.x); o.y = f2bf(v.y); o.z = f2bf(v.z); o.w = f2bf(v.w);
  *reinterpret_cast<ushort4*>(dst + i) = o;
}

// ---------------- GEMM: C[m,n] = sum_k A[m,k]*W[n,k] + bias[n] ----------------
// A: [M,K] row-major, fp32 (AFP32=1, converted in-register) or bf16 (AFP32=0).
// W: [N,K] bf16 row-major. MODE 0: bf16 out [B,H,S,DKH] scaled; MODE 1: bf16 out
// [B,H,DKH,S] (V transposed); MODE 2: f32 out [M,N].
template<int MODE, int AFP32>
__global__ __launch_bounds__(256)
void gemm_bt(const void* __restrict__ Av, const unsigned short* __restrict__ Bw,
             const float* __restrict__ bias, void* __restrict__ out, float scale)
{
  const int K = 1024;
  __shared__ short a_sh[128*64];
  __shared__ short b_sh[128*64];
  const int tid  = threadIdx.x;
  const int lane = tid & 63;
  const int wid  = tid >> 6;
  const int wm = wid >> 1, wn = wid & 1;           // 2x2 waves -> 64x64 each
  const int tileM = blockIdx.x * 128;
  const int tileN = blockIdx.y * 128;

  f32x4 acc[4][4];
  #pragma unroll
  for (int i = 0; i < 4; i++)
    #pragma unroll
    for (int j = 0; j < 4; j++)
      acc[i][j] = (f32x4){0.f,0.f,0.f,0.f};

  const int lr = lane & 15;
  const int lg = lane >> 4;

  for (int k0 = 0; k0 < K; k0 += 64){
    bf16x8 ra[4], rb[4];
    #pragma unroll
    for (int i = 0; i < 4; i++){
      int v   = tid + 256*i;        // 0..1023
      int row = v >> 3;             // 0..127
      int cg  = v & 7;              // 8-bf16 column group
      if constexpr (AFP32){
        const float* Af = (const float*)Av;
        const float4 f0 = *reinterpret_cast<const float4*>(Af + (size_t)(tileM+row)*K + k0 + cg*8);
        const float4 f1 = *reinterpret_cast<const float4*>(Af + (size_t)(tileM+row)*K + k0 + cg*8 + 4);
        ra[i] = cvtA8(f0, f1);
      } else {
        ra[i] = *reinterpret_cast<const bf16x8*>((const unsigned short*)Av + (size_t)(tileM+row)*K + k0 + cg*8);
      }
      rb[i] = *reinterpret_cast<const bf16x8*>(Bw + (size_t)(tileN+row)*K + k0 + cg*8);
    }
    __syncthreads();
    #pragma unroll
    for (int i = 0; i < 4; i++){
      int v   = tid + 256*i;
      int row = v >> 3;
      int cg  = v & 7;
      *reinterpret_cast<bf16x8*>(&a_sh[row*64 + ((cg ^ (row & 7)) * 8)]) = ra[i];
      *reinterpret_cast<bf16x8*>(&b_sh[row*64 + ((cg ^ (row & 7)) * 8)]) = rb[i];
    }
    __syncthreads();
    #pragma unroll
    for (int kk = 0; kk < 64; kk += 32){
      bf16x8 af[4], bfr[4];
      const int g0 = lg + (kk >> 3);
      #pragma unroll
      for (int fm = 0; fm < 4; fm++){
        int row = wm*64 + fm*16 + lr;
        af[fm] = *reinterpret_cast<const bf16x8*>(&a_sh[row*64 + ((g0 ^ (row & 7)) * 8)]);
      }
      #pragma unroll
      for (int fn = 0; fn < 4; fn++){
        int row = wn*64 + fn*16 + lr;
        bfr[fn] = *reinterpret_cast<const bf16x8*>(&b_sh[row*64 + ((g0 ^ (row & 7)) * 8)]);
      }
      #pragma unroll
      for (int fm = 0; fm < 4; fm++)
        #pragma unroll
        for (int fn = 0; fn < 4; fn++)
          acc[fm][fn] = __builtin_amdgcn_mfma_f32_16x16x32_bf16(af[fm], bfr[fn], acc[fm][fn], 0, 0, 0);
    }
  }

  #pragma unroll
  for (int fm = 0; fm < 4; fm++){
    #pragma unroll
    for (int fn = 0; fn < 4; fn++){
      #pragma unroll
      for (int r = 0; r < 4; r++){
        int m = tileM + wm*64 + fm*16 + lg*4 + r;
        int n = tileN + wn*64 + fn*16 + lr;
        float val = acc[fm][fn][r] + bias[n];
        if (MODE == 0){
          val *= scale;
          int b = m >> 11, s = m & 2047, h = n >> 6, d = n & 63;
          ((unsigned short*)out)[(((size_t)(b*NHEADS + h)*SEQ + s)*DKH + d)] = f2bf(val);
        } else if (MODE == 1){
          int b = m >> 11, s = m & 2047, h = n >> 6, d = n & 63;
          ((unsigned short*)out)[(((size_t)(b*NHEADS + h)*DKH + d)*SEQ + s)] = f2bf(val);
        } else {
          ((float*)out)[(size_t)m*DM + n] = val;
        }
      }
    }
  }
}

// ---------------- flash attention (causal), LDS-staged, 128 q-rows/block ----------------
// Q,K: [B,H,S,DKH] bf16 (Q pre-scaled by log2e/sqrt(dk)). Vt: [B,H,DKH,S] bf16.
// exp2-domain softmax, always-rescale. Per-qg processing to keep st live-range short
// (VGPR-spill fix). l-sum via ones-MFMA on the matrix pipe.
__global__ __launch_bounds__(256, 4)
void attn_kernel(const unsigned short* __restrict__ Q, const unsigned short* __restrict__ Kb,
                 const unsigned short* __restrict__ Vt, unsigned short* __restrict__ Oout)
{
  __shared__ unsigned short k_sh[2][64*64];   // [k row][d], XOR-swizzled 16B groups
  __shared__ unsigned short v_sh[2][64*64];   // [d][k col], XOR-swizzled 16B groups
  const int lane = threadIdx.x & 63;
  const int w    = threadIdx.x >> 6;
  const int lr = lane & 15, grp = lane >> 4;
  const int bh = blockIdx.x;                  // 0..63
  const int qtile = 15 - (int)blockIdx.y;     // heavy-first dispatch
  const int qb0 = qtile * 128;
  const int qw0 = qb0 + w * 32;               // wave's first q row
  const int b = bh >> 4, h = bh & 15;
  const size_t kbase = (size_t)bh * SEQ * DKH;
  const size_t vbase = (size_t)bh * DKH * SEQ;

  // staging source offsets (pre-swizzled: linear LDS dest == swizzled layout)
  const int r8 = lane >> 3, c8 = lane & 7;
  const int rowS0 = w*16 + r8;
  const int rowS1 = w*16 + 8 + r8;
  const size_t offK0 = (size_t)rowS0*DKH  + (size_t)((c8 ^ (rowS0 & 7)) * 8);
  const size_t offK1 = (size_t)rowS1*DKH  + (size_t)((c8 ^ (rowS1 & 7)) * 8);
  const size_t offV0 = (size_t)rowS0*SEQ  + (size_t)((c8 ^ (rowS0 & 7)) * 8);
  const size_t offV1 = (size_t)rowS1*SEQ  + (size_t)((c8 ^ (rowS1 & 7)) * 8);
  const int ldsA = (w*16)*64;
  const int ldsB = (w*16+8)*64;

  // Q fragments (registers for whole kernel)
  bf16x8 qf[2][2];
  #pragma unroll
  for (int qg = 0; qg < 2; qg++){
    size_t off = kbase + (size_t)(qw0 + qg*16 + lr)*DKH + grp*8;
    qf[qg][0] = *reinterpret_cast<const bf16x8*>(Q + off);
    qf[qg][1] = *reinterpret_cast<const bf16x8*>(Q + off + 32);
  }

  bf16x4 ones4;
  ones4[0] = (short)0x3F80; ones4[1] = (short)0x3F80;
  ones4[2] = (short)0x3F80; ones4[3] = (short)0x3F80;

  float mrun[2] = {-__builtin_inff(), -__builtin_inff()};
  f32x4 ls[2];
  f32x4 o[2][4];
  #pragma unroll
  for (int qg = 0; qg < 2; qg++){
    ls[qg] = (f32x4){0.f,0.f,0.f,0.f};
    #pragma unroll
    for (int dc = 0; dc < 4; dc++) o[qg][dc] = (f32x4){0.f,0.f,0.f,0.f};
  }

  const int nkb = qb0/64 + 2;

#define STAGE(kb_, bf_) do { \
    gload16(Kb + kbase + (size_t)(kb_)*4096 + offK0, (unsigned short*)&k_sh[bf_][ldsA]); \
    gload16(Kb + kbase + (size_t)(kb_)*4096 + offK1, (unsigned short*)&k_sh[bf_][ldsB]); \
    gload16(Vt + vbase + (size_t)(kb_)*64   + offV0, (unsigned short*)&v_sh[bf_][ldsA]); \
    gload16(Vt + vbase + (size_t)(kb_)*64   + offV1, (unsigned short*)&v_sh[bf_][ldsB]); \
  } while(0)

  STAGE(0, 0);
  __syncthreads();

  for (int kb = 0; kb < nkb; kb++){
    const int buf = kb & 1;
    if (kb + 1 < nkb) STAGE(kb + 1, buf ^ 1);

    if (kb*64 <= qw0 + 31){
      const unsigned short* ks = k_sh[buf];
      const unsigned short* vs = v_sh[buf];
      const bool act0 = (kb*64 <= qw0 + 15);

      bf16x4 pb[2][4];
      // ---- per q-group: QK^T then softmax (keeps st live-range short) ----
      #pragma unroll
      for (int qg = 0; qg < 2; qg++){
        if (qg == 0 && !act0) continue;
        f32x4 st[4];
        __builtin_amdgcn_s_setprio(1);
        #pragma unroll
        for (int ksub = 0; ksub < 4; ksub++){
          int rowk = ksub*16 + lr;
          bf16x8 kf0 = *reinterpret_cast<const bf16x8*>(&ks[rowk*64 + ((grp ^ (rowk & 7)) * 8)]);
          bf16x8 kf1 = *reinterpret_cast<const bf16x8*>(&ks[rowk*64 + (((4 + grp) ^ (rowk & 7)) * 8)]);
          f32x4 s = (f32x4){0.f,0.f,0.f,0.f};
          s = __builtin_amdgcn_mfma_f32_16x16x32_bf16(kf0, qf[qg][0], s, 0, 0, 0);
          s = __builtin_amdgcn_mfma_f32_16x16x32_bf16(kf1, qf[qg][1], s, 0, 0, 0);
          st[ksub] = s;
        }
        __builtin_amdgcn_s_setprio(0);

        const int qgb = qw0 + qg*16;
        if (kb*64 + 63 > qgb){   // diagonal: causal mask
          #pragma unroll
          for (int ksub = 0; ksub < 4; ksub++)
            #pragma unroll
            for (int r = 0; r < 4; r++){
              int kg = kb*64 + ksub*16 + grp*4 + r;
              if (kg > qgb + lr) st[ksub][r] = -__builtin_inff();
            }
        }
        float mt = fmaxf(fmaxf(st[0][0], st[0][1]), fmaxf(st[0][2], st[0][3]));
        #pragma unroll
        for (int ksub = 1; ksub < 4; ksub++){
          mt = fmaxf(mt, fmaxf(fmaxf(st[ksub][0], st[ksub][1]),
                               fmaxf(st[ksub][2], st[ksub][3])));
        }
        mt = fmaxf(mt, __shfl_xor(mt, 16));
        mt = fmaxf(mt, __shfl_xor(mt, 32));
        const float mnew = fmaxf(mrun[qg], mt);
        const float corr = EXP2(mrun[qg] - mnew);   // exp2(-inf)=0 at first tile
        mrun[qg] = mnew;
        #pragma unroll
        for (int dc = 0; dc < 4; dc++){
          o[qg][dc][0] *= corr; o[qg][dc][1] *= corr;
          o[qg][dc][2] *= corr; o[qg][dc][3] *= corr;
        }
        ls[qg][0] *= corr;
        #pragma unroll
        for (int ksub = 0; ksub < 4; ksub++){
          float p0 = EXP2(st[ksub][0] - mnew);
          float p1 = EXP2(st[ksub][1] - mnew);
          float p2 = EXP2(st[ksub][2] - mnew);
          float p3 = EXP2(st[ksub][3] - mnew);
          union { unsigned u[2]; bf16x4 v; } pk;
          pk.u[0] = pk2bf(p0, p1);
          pk.u[1] = pk2bf(p2, p3);
          pb[qg][ksub] = pk.v;
        }
      }

      // ---- PV + l-sum on the matrix pipe ----
      __builtin_amdgcn_s_setprio(1);
      #pragma unroll
      for (int ksub = 0; ksub < 4; ksub++){
        #pragma unroll
        for (int dc = 0; dc < 4; dc++){
          int rowd = dc*16 + lr;
          int cg16 = ksub*2 + (grp >> 1);
          bf16x4 vf = *reinterpret_cast<const bf16x4*>(
              &vs[rowd*64 + ((cg16 ^ (rowd & 7)) * 8) + (grp & 1)*4]);
          if (act0) o[0][dc] = __builtin_amdgcn_mfma_f32_16x16x16bf16_1k(vf, pb[0][ksub], o[0][dc], 0, 0, 0);
          o[1][dc] = __builtin_amdgcn_mfma_f32_16x16x16bf16_1k(vf, pb[1][ksub], o[1][dc], 0, 0, 0);
        }
        if (act0) ls[0] = __builtin_amdgcn_mfma_f32_16x16x16bf16_1k(ones4, pb[0][ksub], ls[0], 0, 0, 0);
        ls[1] = __builtin_amdgcn_mfma_f32_16x16x16bf16_1k(ones4, pb[1][ksub], ls[1], 0, 0, 0);
      }
      __builtin_amdgcn_s_setprio(0);
    }
    __syncthreads();
  }
#undef STAGE

  // ---- epilogue ----
  #pragma unroll
  for (int qg = 0; qg < 2; qg++){
    float inv = 1.0f / ls[qg][0];
    int qglob = qw0 + qg*16 + lr;
    size_t ob = ((size_t)(b*SEQ + qglob))*DM + h*DKH;
    #pragma unroll
    for (int dc = 0; dc < 4; dc++){
      ushort4 pk;
      pk.x = f2bf(o[qg][dc][0]*inv);
      pk.y = f2bf(o[qg][dc][1]*inv);
      pk.z = f2bf(o[qg][dc][2]*inv);
      pk.w = f2bf(o[qg][dc][3]*inv);
      *reinterpret_cast<ushort4*>(&Oout[ob + dc*16 + grp*4]) = pk;
    }
  }
}

extern "C" void kernel_launch(void* const* d_in, const int* in_sizes, int n_in,
                              void* d_out, int out_size, void* d_ws, size_t ws_size,
                              hipStream_t stream) {
  const float* query = (const float*)d_in[0];
  const float* key   = (const float*)d_in[1];
  const float* value = (const float*)d_in[2];
  const float* Wq = (const float*)d_in[4];
  const float* bq = (const float*)d_in[5];
  const float* Wk = (const float*)d_in[6];
  const float* bk = (const float*)d_in[7];
  const float* Wv = (const float*)d_in[8];
  const float* bv = (const float*)d_in[9];
  const float* Wo = (const float*)d_in[10];
  const float* bo = (const float*)d_in[11];
  float* out = (float*)d_out;

  char* ws = (char*)d_ws;
  const size_t SZ_X = (size_t)MROWS * DM * 2;   // 16 MB
  const size_t SZ_W = (size_t)DM * DM * 2;      // 2 MB
  unsigned short* wqb = (unsigned short*)(ws + 0);
  unsigned short* wkb = (unsigned short*)(ws + SZ_W);
  unsigned short* wvb = (unsigned short*)(ws + 2*SZ_W);
  unsigned short* wob = (unsigned short*)(ws + 3*SZ_W);
  unsigned short* Qb   = (unsigned short*)(ws + 4*SZ_W);
  unsigned short* Kbuf = (unsigned short*)(ws + 4*SZ_W + SZ_X);
  unsigned short* Vt   = (unsigned short*)(ws + 4*SZ_W + 2*SZ_X);
  unsigned short* attO = (unsigned short*)(ws + 4*SZ_W + 3*SZ_X);  // total 72 MB

  ConvArgs ca;
  ca.src[0] = Wq; ca.src[1] = Wk; ca.src[2] = Wv; ca.src[3] = Wo;
  ca.dst[0] = wqb; ca.dst[1] = wkb; ca.dst[2] = wvb; ca.dst[3] = wob;
  conv_w<<<4096, 256, 0, stream>>>(ca);

  dim3 gg(MROWS/128, DM/128);   // (64, 8)
  const float qscale = 0.125f * 1.4426950408889634f;   // 1/sqrt(dk) * log2(e)
  gemm_bt<1,1><<<gg, 256, 0, stream>>>(value, wvb, bv, (void*)Vt,   1.0f);
  gemm_bt<0,1><<<gg, 256, 0, stream>>>(query, wqb, bq, (void*)Qb,   qscale);
  gemm_bt<0,1><<<gg, 256, 0, stream>>>(key,   wkb, bk, (void*)Kbuf, 1.0f);

  attn_kernel<<<dim3(64, 16), 256, 0, stream>>>(Qb, Kbuf, Vt, attO);

  gemm_bt<2,0><<<gg, 256, 0, stream>>>(attO, wob, bo, (void*)out, 1.0f);
}

// Round 6
// 198.704 us; speedup vs baseline: 4.0136x; 1.0073x over previous
//
#include <hip/hip_runtime.h>
#include <hip/hip_bf16.h>

#define DM 1024
#define NHEADS 16
#define DKH 64
#define BATCH 4
#define SEQ 2048
#define MROWS (BATCH*SEQ)   // 8192

typedef __attribute__((ext_vector_type(8))) short bf16x8;
typedef __attribute__((ext_vector_type(4))) short bf16x4;
typedef __attribute__((ext_vector_type(4))) float f32x4;

#if __has_builtin(__builtin_amdgcn_exp2f)
#define EXP2(x) __builtin_amdgcn_exp2f(x)
#else
#define EXP2(x) exp2f(x)
#endif

__device__ __forceinline__ unsigned short f2bf(float f){
  unsigned u = __float_as_uint(f);
  u += 0x7fffu + ((u >> 16) & 1u);   // RNE
  return (unsigned short)(u >> 16);
}

__device__ __forceinline__ unsigned pk2bf(float lo, float hi){
  union { __hip_bfloat162 h; unsigned u; } c;
  c.h = __float22bfloat162_rn(make_float2(lo, hi));   // v_cvt_pk_bf16_f32 (RNE)
  return c.u;
}

__device__ __forceinline__ bf16x8 cvtA8(float4 a, float4 b){
  union { unsigned u[4]; bf16x8 v; } r;
  r.u[0] = pk2bf(a.x, a.y);
  r.u[1] = pk2bf(a.z, a.w);
  r.u[2] = pk2bf(b.x, b.y);
  r.u[3] = pk2bf(b.z, b.w);
  return r.v;
}

__device__ __forceinline__ void gload16(const unsigned short* g, unsigned short* l){
  __builtin_amdgcn_global_load_lds((const __attribute__((address_space(1))) void*)g,
                                   (__attribute__((address_space(3))) void*)l, 16, 0, 0);
}

// ---------------- fp32 -> bf16 conversion (4 weight matrices only) ----------------
struct ConvArgs { const float* src[4]; unsigned short* dst[4]; };

__global__ __launch_bounds__(256) void conv_w(ConvArgs a){
  const int t = blockIdx.x >> 10;          // 4 tensors x 1024 blocks
  const int boff = blockIdx.x & 1023;
  const float* __restrict__ src = a.src[t];
  unsigned short* __restrict__ dst = a.dst[t];
  const int i = (boff * 256 + threadIdx.x) * 4;
  const float4 v = *reinterpret_cast<const float4*>(src + i);
  ushort4 o;
  o.x = f2bf(v.x); o.y = f2bf(v.y); o.z = f2bf(v.z); o.w = f2bf(v.w);
  *reinterpret_cast<ushort4*>(dst + i) = o;
}

// ---------------- GEMM: C[m,n] = sum_k A[m,k]*W[n,k] + bias[n] ----------------
// A: [M,K] row-major, fp32 (AFP32=1, reg-converted) or bf16 (AFP32=0, gload_lds).
// W: [N,K] bf16 row-major, staged via global_load_lds with pre-swizzled source.
// MODE 0: bf16 out [B,H,S,DKH] scaled; MODE 1: bf16 out [B,H,DKH,S]; MODE 2: f32 [M,N].
template<int MODE, int AFP32>
__global__ __launch_bounds__(256)
void gemm_bt(const void* __restrict__ Av, const unsigned short* __restrict__ Bw,
             const float* __restrict__ bias, void* __restrict__ out, float scale)
{
  const int K = 1024;
  __shared__ short a_sh[128*64];
  __shared__ short b_sh[128*64];
  const int tid  = threadIdx.x;
  const int lane = tid & 63;
  const int wid  = tid >> 6;
  const int wm = wid >> 1, wn = wid & 1;           // 2x2 waves -> 64x64 each
  const int tileM = blockIdx.x * 128;
  const int tileN = blockIdx.y * 128;

  f32x4 acc[4][4];
  #pragma unroll
  for (int i = 0; i < 4; i++)
    #pragma unroll
    for (int j = 0; j < 4; j++)
      acc[i][j] = (f32x4){0.f,0.f,0.f,0.f};

  const int lr = lane & 15;
  const int lg = lane >> 4;

  // gload staging geometry: call j (0..3), wave wid stages rows 32j+8*wid .. +7.
  // row & 7 == lane>>3 (32j, 8*wid are mult. of 8) -> swizzle XOR is lane-constant.
  const int r8 = lane >> 3, c8 = lane & 7;
  const int srow = 8*wid + r8;                 // + 32j per call
  const int sgrp = (c8 ^ r8) * 8;              // pre-swizzled source column group

  for (int k0 = 0; k0 < K; k0 += 64){
    bf16x8 ra[4];
    if constexpr (AFP32){
      // A fp32 loads issued before the barrier (overlap barrier wait)
      const float* Af = (const float*)Av;
      #pragma unroll
      for (int i = 0; i < 4; i++){
        int v   = tid + 256*i;
        int row = v >> 3;
        int cg  = v & 7;
        const float4 f0 = *reinterpret_cast<const float4*>(Af + (size_t)(tileM+row)*K + k0 + cg*8);
        const float4 f1 = *reinterpret_cast<const float4*>(Af + (size_t)(tileM+row)*K + k0 + cg*8 + 4);
        ra[i] = cvtA8(f0, f1);
      }
    }
    __syncthreads();   // LDS free (consumers of previous tile done)
    // B tile via global_load_lds (pre-swizzled source, linear LDS dest)
    #pragma unroll
    for (int j = 0; j < 4; j++){
      gload16(Bw + (size_t)(tileN + srow + 32*j)*K + k0 + sgrp,
              (unsigned short*)&b_sh[(8*wid + 32*j)*64]);
    }
    if constexpr (AFP32){
      #pragma unroll
      for (int i = 0; i < 4; i++){
        int v   = tid + 256*i;
        int row = v >> 3;
        int cg  = v & 7;
        *reinterpret_cast<bf16x8*>(&a_sh[row*64 + ((cg ^ (row & 7)) * 8)]) = ra[i];
      }
    } else {
      const unsigned short* Ab = (const unsigned short*)Av;
      #pragma unroll
      for (int j = 0; j < 4; j++){
        gload16(Ab + (size_t)(tileM + srow + 32*j)*K + k0 + sgrp,
                (unsigned short*)&a_sh[(8*wid + 32*j)*64]);
      }
    }
    __syncthreads();   // drains vmcnt (gload_lds) + lgkm (ds_write)

    #pragma unroll
    for (int kk = 0; kk < 64; kk += 32){
      bf16x8 af[4], bfr[4];
      const int g0 = lg + (kk >> 3);
      #pragma unroll
      for (int fm = 0; fm < 4; fm++){
        int row = wm*64 + fm*16 + lr;
        af[fm] = *reinterpret_cast<const bf16x8*>(&a_sh[row*64 + ((g0 ^ (row & 7)) * 8)]);
      }
      #pragma unroll
      for (int fn = 0; fn < 4; fn++){
        int row = wn*64 + fn*16 + lr;
        bfr[fn] = *reinterpret_cast<const bf16x8*>(&b_sh[row*64 + ((g0 ^ (row & 7)) * 8)]);
      }
      #pragma unroll
      for (int fm = 0; fm < 4; fm++)
        #pragma unroll
        for (int fn = 0; fn < 4; fn++)
          acc[fm][fn] = __builtin_amdgcn_mfma_f32_16x16x32_bf16(af[fm], bfr[fn], acc[fm][fn], 0, 0, 0);
    }
  }

  #pragma unroll
  for (int fm = 0; fm < 4; fm++){
    #pragma unroll
    for (int fn = 0; fn < 4; fn++){
      #pragma unroll
      for (int r = 0; r < 4; r++){
        int m = tileM + wm*64 + fm*16 + lg*4 + r;
        int n = tileN + wn*64 + fn*16 + lr;
        float val = acc[fm][fn][r] + bias[n];
        if (MODE == 0){
          val *= scale;
          int b = m >> 11, s = m & 2047, h = n >> 6, d = n & 63;
          ((unsigned short*)out)[(((size_t)(b*NHEADS + h)*SEQ + s)*DKH + d)] = f2bf(val);
        } else if (MODE == 1){
          int b = m >> 11, s = m & 2047, h = n >> 6, d = n & 63;
          ((unsigned short*)out)[(((size_t)(b*NHEADS + h)*DKH + d)*SEQ + s)] = f2bf(val);
        } else {
          ((float*)out)[(size_t)m*DM + n] = val;
        }
      }
    }
  }
}

// ---------------- flash attention (causal), LDS-staged, 128 q-rows/block ----------------
// Q,K: [B,H,S,DKH] bf16 (Q pre-scaled by log2e/sqrt(dk)). Vt: [B,H,DKH,S] bf16.
// exp2-domain softmax, always-rescale. Per-qg processing keeps st live-range short.
__global__ __launch_bounds__(256, 4)
void attn_kernel(const unsigned short* __restrict__ Q, const unsigned short* __restrict__ Kb,
                 const unsigned short* __restrict__ Vt, unsigned short* __restrict__ Oout)
{
  __shared__ unsigned short k_sh[2][64*64];   // [k row][d], XOR-swizzled 16B groups
  __shared__ unsigned short v_sh[2][64*64];   // [d][k col], XOR-swizzled 16B groups
  const int lane = threadIdx.x & 63;
  const int w    = threadIdx.x >> 6;
  const int lr = lane & 15, grp = lane >> 4;
  const int bh = blockIdx.x;                  // 0..63
  const int qtile = 15 - (int)blockIdx.y;     // heavy-first dispatch
  const int qb0 = qtile * 128;
  const int qw0 = qb0 + w * 32;               // wave's first q row
  const int b = bh >> 4, h = bh & 15;
  const size_t kbase = (size_t)bh * SEQ * DKH;
  const size_t vbase = (size_t)bh * DKH * SEQ;

  // staging source offsets (pre-swizzled: linear LDS dest == swizzled layout)
  const int r8 = lane >> 3, c8 = lane & 7;
  const int rowS0 = w*16 + r8;
  const int rowS1 = w*16 + 8 + r8;
  const size_t offK0 = (size_t)rowS0*DKH  + (size_t)((c8 ^ (rowS0 & 7)) * 8);
  const size_t offK1 = (size_t)rowS1*DKH  + (size_t)((c8 ^ (rowS1 & 7)) * 8);
  const size_t offV0 = (size_t)rowS0*SEQ  + (size_t)((c8 ^ (rowS0 & 7)) * 8);
  const size_t offV1 = (size_t)rowS1*SEQ  + (size_t)((c8 ^ (rowS1 & 7)) * 8);
  const int ldsA = (w*16)*64;
  const int ldsB = (w*16+8)*64;

  // Q fragments (registers for whole kernel)
  bf16x8 qf[2][2];
  #pragma unroll
  for (int qg = 0; qg < 2; qg++){
    size_t off = kbase + (size_t)(qw0 + qg*16 + lr)*DKH + grp*8;
    qf[qg][0] = *reinterpret_cast<const bf16x8*>(Q + off);
    qf[qg][1] = *reinterpret_cast<const bf16x8*>(Q + off + 32);
  }

  bf16x4 ones4;
  ones4[0] = (short)0x3F80; ones4[1] = (short)0x3F80;
  ones4[2] = (short)0x3F80; ones4[3] = (short)0x3F80;

  float mrun[2] = {-__builtin_inff(), -__builtin_inff()};
  f32x4 ls[2];
  f32x4 o[2][4];
  #pragma unroll
  for (int qg = 0; qg < 2; qg++){
    ls[qg] = (f32x4){0.f,0.f,0.f,0.f};
    #pragma unroll
    for (int dc = 0; dc < 4; dc++) o[qg][dc] = (f32x4){0.f,0.f,0.f,0.f};
  }

  const int nkb = qb0/64 + 2;

#define STAGE(kb_, bf_) do { \
    gload16(Kb + kbase + (size_t)(kb_)*4096 + offK0, (unsigned short*)&k_sh[bf_][ldsA]); \
    gload16(Kb + kbase + (size_t)(kb_)*4096 + offK1, (unsigned short*)&k_sh[bf_][ldsB]); \
    gload16(Vt + vbase + (size_t)(kb_)*64   + offV0, (unsigned short*)&v_sh[bf_][ldsA]); \
    gload16(Vt + vbase + (size_t)(kb_)*64   + offV1, (unsigned short*)&v_sh[bf_][ldsB]); \
  } while(0)

  STAGE(0, 0);
  __syncthreads();

  for (int kb = 0; kb < nkb; kb++){
    const int buf = kb & 1;
    if (kb + 1 < nkb) STAGE(kb + 1, buf ^ 1);

    if (kb*64 <= qw0 + 31){
      const unsigned short* ks = k_sh[buf];
      const unsigned short* vs = v_sh[buf];
      const bool act0 = (kb*64 <= qw0 + 15);

      bf16x4 pb[2][4];
      // ---- per q-group: QK^T then softmax (keeps st live-range short) ----
      #pragma unroll
      for (int qg = 0; qg < 2; qg++){
        if (qg == 0 && !act0) continue;
        f32x4 st[4];
        __builtin_amdgcn_s_setprio(1);
        #pragma unroll
        for (int ksub = 0; ksub < 4; ksub++){
          int rowk = ksub*16 + lr;
          bf16x8 kf0 = *reinterpret_cast<const bf16x8*>(&ks[rowk*64 + ((grp ^ (rowk & 7)) * 8)]);
          bf16x8 kf1 = *reinterpret_cast<const bf16x8*>(&ks[rowk*64 + (((4 + grp) ^ (rowk & 7)) * 8)]);
          f32x4 s = (f32x4){0.f,0.f,0.f,0.f};
          s = __builtin_amdgcn_mfma_f32_16x16x32_bf16(kf0, qf[qg][0], s, 0, 0, 0);
          s = __builtin_amdgcn_mfma_f32_16x16x32_bf16(kf1, qf[qg][1], s, 0, 0, 0);
          st[ksub] = s;
        }
        __builtin_amdgcn_s_setprio(0);

        const int qgb = qw0 + qg*16;
        if (kb*64 + 63 > qgb){   // diagonal: causal mask
          #pragma unroll
          for (int ksub = 0; ksub < 4; ksub++)
            #pragma unroll
            for (int r = 0; r < 4; r++){
              int kg = kb*64 + ksub*16 + grp*4 + r;
              if (kg > qgb + lr) st[ksub][r] = -__builtin_inff();
            }
        }
        float mt = fmaxf(fmaxf(st[0][0], st[0][1]), fmaxf(st[0][2], st[0][3]));
        #pragma unroll
        for (int ksub = 1; ksub < 4; ksub++){
          mt = fmaxf(mt, fmaxf(fmaxf(st[ksub][0], st[ksub][1]),
                               fmaxf(st[ksub][2], st[ksub][3])));
        }
        mt = fmaxf(mt, __shfl_xor(mt, 16));
        mt = fmaxf(mt, __shfl_xor(mt, 32));
        const float mnew = fmaxf(mrun[qg], mt);
        const float corr = EXP2(mrun[qg] - mnew);   // exp2(-inf)=0 at first tile
        mrun[qg] = mnew;
        #pragma unroll
        for (int dc = 0; dc < 4; dc++){
          o[qg][dc][0] *= corr; o[qg][dc][1] *= corr;
          o[qg][dc][2] *= corr; o[qg][dc][3] *= corr;
        }
        ls[qg][0] *= corr;
        #pragma unroll
        for (int ksub = 0; ksub < 4; ksub++){
          float p0 = EXP2(st[ksub][0] - mnew);
          float p1 = EXP2(st[ksub][1] - mnew);
          float p2 = EXP2(st[ksub][2] - mnew);
          float p3 = EXP2(st[ksub][3] - mnew);
          union { unsigned u[2]; bf16x4 v; } pk;
          pk.u[0] = pk2bf(p0, p1);
          pk.u[1] = pk2bf(p2, p3);
          pb[qg][ksub] = pk.v;
        }
      }

      // ---- PV + l-sum on the matrix pipe ----
      __builtin_amdgcn_s_setprio(1);
      #pragma unroll
      for (int ksub = 0; ksub < 4; ksub++){
        #pragma unroll
        for (int dc = 0; dc < 4; dc++){
          int rowd = dc*16 + lr;
          int cg16 = ksub*2 + (grp >> 1);
          bf16x4 vf = *reinterpret_cast<const bf16x4*>(
              &vs[rowd*64 + ((cg16 ^ (rowd & 7)) * 8) + (grp & 1)*4]);
          if (act0) o[0][dc] = __builtin_amdgcn_mfma_f32_16x16x16bf16_1k(vf, pb[0][ksub], o[0][dc], 0, 0, 0);
          o[1][dc] = __builtin_amdgcn_mfma_f32_16x16x16bf16_1k(vf, pb[1][ksub], o[1][dc], 0, 0, 0);
        }
        if (act0) ls[0] = __builtin_amdgcn_mfma_f32_16x16x16bf16_1k(ones4, pb[0][ksub], ls[0], 0, 0, 0);
        ls[1] = __builtin_amdgcn_mfma_f32_16x16x16bf16_1k(ones4, pb[1][ksub], ls[1], 0, 0, 0);
      }
      __builtin_amdgcn_s_setprio(0);
    }
    __syncthreads();
  }
#undef STAGE

  // ---- epilogue ----
  #pragma unroll
  for (int qg = 0; qg < 2; qg++){
    float inv = 1.0f / ls[qg][0];
    int qglob = qw0 + qg*16 + lr;
    size_t ob = ((size_t)(b*SEQ + qglob))*DM + h*DKH;
    #pragma unroll
    for (int dc = 0; dc < 4; dc++){
      ushort4 pk;
      pk.x = f2bf(o[qg][dc][0]*inv);
      pk.y = f2bf(o[qg][dc][1]*inv);
      pk.z = f2bf(o[qg][dc][2]*inv);
      pk.w = f2bf(o[qg][dc][3]*inv);
      *reinterpret_cast<ushort4*>(&Oout[ob + dc*16 + grp*4]) = pk;
    }
  }
}

extern "C" void kernel_launch(void* const* d_in, const int* in_sizes, int n_in,
                              void* d_out, int out_size, void* d_ws, size_t ws_size,
                              hipStream_t stream) {
  const float* query = (const float*)d_in[0];
  const float* key   = (const float*)d_in[1];
  const float* value = (const float*)d_in[2];
  const float* Wq = (const float*)d_in[4];
  const float* bq = (const float*)d_in[5];
  const float* Wk = (const float*)d_in[6];
  const float* bk = (const float*)d_in[7];
  const float* Wv = (const float*)d_in[8];
  const float* bv = (const float*)d_in[9];
  const float* Wo = (const float*)d_in[10];
  const float* bo = (const float*)d_in[11];
  float* out = (float*)d_out;

  char* ws = (char*)d_ws;
  const size_t SZ_X = (size_t)MROWS * DM * 2;   // 16 MB
  const size_t SZ_W = (size_t)DM * DM * 2;      // 2 MB
  unsigned short* wqb = (unsigned short*)(ws + 0);
  unsigned short* wkb = (unsigned short*)(ws + SZ_W);
  unsigned short* wvb = (unsigned short*)(ws + 2*SZ_W);
  unsigned short* wob = (unsigned short*)(ws + 3*SZ_W);
  unsigned short* Qb   = (unsigned short*)(ws + 4*SZ_W);
  unsigned short* Kbuf = (unsigned short*)(ws + 4*SZ_W + SZ_X);
  unsigned short* Vt   = (unsigned short*)(ws + 4*SZ_W + 2*SZ_X);
  unsigned short* attO = (unsigned short*)(ws + 4*SZ_W + 3*SZ_X);  // total 72 MB

  ConvArgs ca;
  ca.src[0] = Wq; ca.src[1] = Wk; ca.src[2] = Wv; ca.src[3] = Wo;
  ca.dst[0] = wqb; ca.dst[1] = wkb; ca.dst[2] = wvb; ca.dst[3] = wob;
  conv_w<<<4096, 256, 0, stream>>>(ca);

  dim3 gg(MROWS/128, DM/128);   // (64, 8)
  const float qscale = 0.125f * 1.4426950408889634f;   // 1/sqrt(dk) * log2(e)
  gemm_bt<1,1><<<gg, 256, 0, stream>>>(value, wvb, bv, (void*)Vt,   1.0f);
  gemm_bt<0,1><<<gg, 256, 0, stream>>>(query, wqb, bq, (void*)Qb,   qscale);
  gemm_bt<0,1><<<gg, 256, 0, stream>>>(key,   wkb, bk, (void*)Kbuf, 1.0f);

  attn_kernel<<<dim3(64, 16), 256, 0, stream>>>(Qb, Kbuf, Vt, attO);

  gemm_bt<2,0><<<gg, 256, 0, stream>>>(attO, wob, bo, (void*)out, 1.0f);
}

// Round 7
// 198.569 us; speedup vs baseline: 4.0163x; 1.0007x over previous
//
#include <hip/hip_runtime.h>
#include <hip/hip_bf16.h>

#define DM 1024
#define NHEADS 16
#define DKH 64
#define BATCH 4
#define SEQ 2048
#define MROWS (BATCH*SEQ)   // 8192

typedef __attribute__((ext_vector_type(8))) short bf16x8;
typedef __attribute__((ext_vector_type(4))) short bf16x4;
typedef __attribute__((ext_vector_type(4))) float f32x4;

#if __has_builtin(__builtin_amdgcn_exp2f)
#define EXP2(x) __builtin_amdgcn_exp2f(x)
#else
#define EXP2(x) exp2f(x)
#endif

__device__ __forceinline__ unsigned short f2bf(float f){
  unsigned u = __float_as_uint(f);
  u += 0x7fffu + ((u >> 16) & 1u);   // RNE
  return (unsigned short)(u >> 16);
}

__device__ __forceinline__ unsigned pk2bf(float lo, float hi){
  union { __hip_bfloat162 h; unsigned u; } c;
  c.h = __float22bfloat162_rn(make_float2(lo, hi));   // v_cvt_pk_bf16_f32 (RNE)
  return c.u;
}

__device__ __forceinline__ bf16x8 cvtA8(float4 a, float4 b){
  union { unsigned u[4]; bf16x8 v; } r;
  r.u[0] = pk2bf(a.x, a.y);
  r.u[1] = pk2bf(a.z, a.w);
  r.u[2] = pk2bf(b.x, b.y);
  r.u[3] = pk2bf(b.z, b.w);
  return r.v;
}

__device__ __forceinline__ void gload16(const unsigned short* g, unsigned short* l){
  __builtin_amdgcn_global_load_lds((const __attribute__((address_space(1))) void*)g,
                                   (__attribute__((address_space(3))) void*)l, 16, 0, 0);
}

// ---------------- fp32 -> bf16 conversion (4 weight matrices only) ----------------
struct ConvArgs { const float* src[4]; unsigned short* dst[4]; };

__global__ __launch_bounds__(256) void conv_w(ConvArgs a){
  const int t = blockIdx.x >> 10;          // 4 tensors x 1024 blocks
  const int boff = blockIdx.x & 1023;
  const float* __restrict__ src = a.src[t];
  unsigned short* __restrict__ dst = a.dst[t];
  const int i = (boff * 256 + threadIdx.x) * 4;
  const float4 v = *reinterpret_cast<const float4*>(src + i);
  ushort4 o;
  o.x = f2bf(v.x); o.y = f2bf(v.y); o.z = f2bf(v.z); o.w = f2bf(v.w);
  *reinterpret_cast<ushort4*>(dst + i) = o;
}

// ---------------- GEMM: C[m,n] = sum_k A[m,k]*W[n,k] + bias[n] ----------------
// Grid: 512 linear blocks, XCD-locality swizzle: XCD c owns M-panels 8c..8c+7
// x all 8 N-tiles, so its A working set (4 MB) + B (2 MB) stays L2-resident and
// A is fetched from HBM once instead of 8x.
// A: [M,K] row-major, fp32 (AFP32=1, reg-converted) or bf16 (AFP32=0, gload_lds).
// W: [N,K] bf16 row-major, staged via global_load_lds with pre-swizzled source.
// MODE 0: bf16 out [B,H,S,DKH] scaled; MODE 1: bf16 out [B,H,DKH,S]; MODE 2: f32 [M,N].
template<int MODE, int AFP32>
__global__ __launch_bounds__(256)
void gemm_bt(const void* __restrict__ Av, const unsigned short* __restrict__ Bw,
             const float* __restrict__ bias, void* __restrict__ out, float scale)
{
  const int K = 1024;
  __shared__ short a_sh[128*64];
  __shared__ short b_sh[128*64];
  const int tid  = threadIdx.x;
  const int lane = tid & 63;
  const int wid  = tid >> 6;
  const int wm = wid >> 1, wn = wid & 1;           // 2x2 waves -> 64x64 each
  // XCD-locality swizzle (round-robin dispatch: xcd = lin % 8)
  const int lin = blockIdx.x;
  const int xcd = lin & 7;
  const int i9  = lin >> 3;
  const int tileM = (8*xcd + (i9 >> 3)) * 128;
  const int tileN = (i9 & 7) * 128;

  f32x4 acc[4][4];
  #pragma unroll
  for (int i = 0; i < 4; i++)
    #pragma unroll
    for (int j = 0; j < 4; j++)
      acc[i][j] = (f32x4){0.f,0.f,0.f,0.f};

  const int lr = lane & 15;
  const int lg = lane >> 4;

  // gload staging geometry: call j (0..3), wave wid stages rows 32j+8*wid .. +7.
  // row & 7 == lane>>3 -> swizzle XOR is lane-constant.
  const int r8 = lane >> 3, c8 = lane & 7;
  const int srow = 8*wid + r8;                 // + 32j per call
  const int sgrp = (c8 ^ r8) * 8;              // pre-swizzled source column group

  for (int k0 = 0; k0 < K; k0 += 64){
    bf16x8 ra[4];
    if constexpr (AFP32){
      const float* Af = (const float*)Av;
      #pragma unroll
      for (int i = 0; i < 4; i++){
        int v   = tid + 256*i;
        int row = v >> 3;
        int cg  = v & 7;
        const float4 f0 = *reinterpret_cast<const float4*>(Af + (size_t)(tileM+row)*K + k0 + cg*8);
        const float4 f1 = *reinterpret_cast<const float4*>(Af + (size_t)(tileM+row)*K + k0 + cg*8 + 4);
        ra[i] = cvtA8(f0, f1);
      }
    }
    __syncthreads();   // LDS free (consumers of previous tile done)
    // B tile via global_load_lds (pre-swizzled source, linear LDS dest)
    #pragma unroll
    for (int j = 0; j < 4; j++){
      gload16(Bw + (size_t)(tileN + srow + 32*j)*K + k0 + sgrp,
              (unsigned short*)&b_sh[(8*wid + 32*j)*64]);
    }
    if constexpr (AFP32){
      #pragma unroll
      for (int i = 0; i < 4; i++){
        int v   = tid + 256*i;
        int row = v >> 3;
        int cg  = v & 7;
        *reinterpret_cast<bf16x8*>(&a_sh[row*64 + ((cg ^ (row & 7)) * 8)]) = ra[i];
      }
    } else {
      const unsigned short* Ab = (const unsigned short*)Av;
      #pragma unroll
      for (int j = 0; j < 4; j++){
        gload16(Ab + (size_t)(tileM + srow + 32*j)*K + k0 + sgrp,
                (unsigned short*)&a_sh[(8*wid + 32*j)*64]);
      }
    }
    __syncthreads();   // drains vmcnt (gload_lds) + lgkm (ds_write)

    #pragma unroll
    for (int kk = 0; kk < 64; kk += 32){
      bf16x8 af[4], bfr[4];
      const int g0 = lg + (kk >> 3);
      #pragma unroll
      for (int fm = 0; fm < 4; fm++){
        int row = wm*64 + fm*16 + lr;
        af[fm] = *reinterpret_cast<const bf16x8*>(&a_sh[row*64 + ((g0 ^ (row & 7)) * 8)]);
      }
      #pragma unroll
      for (int fn = 0; fn < 4; fn++){
        int row = wn*64 + fn*16 + lr;
        bfr[fn] = *reinterpret_cast<const bf16x8*>(&b_sh[row*64 + ((g0 ^ (row & 7)) * 8)]);
      }
      #pragma unroll
      for (int fm = 0; fm < 4; fm++)
        #pragma unroll
        for (int fn = 0; fn < 4; fn++)
          acc[fm][fn] = __builtin_amdgcn_mfma_f32_16x16x32_bf16(af[fm], bfr[fn], acc[fm][fn], 0, 0, 0);
    }
  }

  #pragma unroll
  for (int fm = 0; fm < 4; fm++){
    #pragma unroll
    for (int fn = 0; fn < 4; fn++){
      #pragma unroll
      for (int r = 0; r < 4; r++){
        int m = tileM + wm*64 + fm*16 + lg*4 + r;
        int n = tileN + wn*64 + fn*16 + lr;
        float val = acc[fm][fn][r] + bias[n];
        if (MODE == 0){
          val *= scale;
          int b = m >> 11, s = m & 2047, h = n >> 6, d = n & 63;
          ((unsigned short*)out)[(((size_t)(b*NHEADS + h)*SEQ + s)*DKH + d)] = f2bf(val);
        } else if (MODE == 1){
          int b = m >> 11, s = m & 2047, h = n >> 6, d = n & 63;
          ((unsigned short*)out)[(((size_t)(b*NHEADS + h)*DKH + d)*SEQ + s)] = f2bf(val);
        } else {
          ((float*)out)[(size_t)m*DM + n] = val;
        }
      }
    }
  }
}

// ---------------- flash attention (causal), LDS-staged, 128 q-rows/block ----------------
// Q,K: [B,H,S,DKH] bf16 (Q pre-scaled by log2e/sqrt(dk)). Vt: [B,H,DKH,S] bf16.
// exp2-domain softmax, always-rescale. Per-qg processing keeps st live-range short.
__global__ __launch_bounds__(256, 4)
void attn_kernel(const unsigned short* __restrict__ Q, const unsigned short* __restrict__ Kb,
                 const unsigned short* __restrict__ Vt, unsigned short* __restrict__ Oout)
{
  __shared__ unsigned short k_sh[2][64*64];   // [k row][d], XOR-swizzled 16B groups
  __shared__ unsigned short v_sh[2][64*64];   // [d][k col], XOR-swizzled 16B groups
  const int lane = threadIdx.x & 63;
  const int w    = threadIdx.x >> 6;
  const int lr = lane & 15, grp = lane >> 4;
  const int bh = blockIdx.x;                  // 0..63
  const int qtile = 15 - (int)blockIdx.y;     // heavy-first dispatch
  const int qb0 = qtile * 128;
  const int qw0 = qb0 + w * 32;               // wave's first q row
  const int b = bh >> 4, h = bh & 15;
  const size_t kbase = (size_t)bh * SEQ * DKH;
  const size_t vbase = (size_t)bh * DKH * SEQ;

  // staging source offsets (pre-swizzled: linear LDS dest == swizzled layout)
  const int r8 = lane >> 3, c8 = lane & 7;
  const int rowS0 = w*16 + r8;
  const int rowS1 = w*16 + 8 + r8;
  const size_t offK0 = (size_t)rowS0*DKH  + (size_t)((c8 ^ (rowS0 & 7)) * 8);
  const size_t offK1 = (size_t)rowS1*DKH  + (size_t)((c8 ^ (rowS1 & 7)) * 8);
  const size_t offV0 = (size_t)rowS0*SEQ  + (size_t)((c8 ^ (rowS0 & 7)) * 8);
  const size_t offV1 = (size_t)rowS1*SEQ  + (size_t)((c8 ^ (rowS1 & 7)) * 8);
  const int ldsA = (w*16)*64;
  const int ldsB = (w*16+8)*64;

  // Q fragments (registers for whole kernel)
  bf16x8 qf[2][2];
  #pragma unroll
  for (int qg = 0; qg < 2; qg++){
    size_t off = kbase + (size_t)(qw0 + qg*16 + lr)*DKH + grp*8;
    qf[qg][0] = *reinterpret_cast<const bf16x8*>(Q + off);
    qf[qg][1] = *reinterpret_cast<const bf16x8*>(Q + off + 32);
  }

  bf16x4 ones4;
  ones4[0] = (short)0x3F80; ones4[1] = (short)0x3F80;
  ones4[2] = (short)0x3F80; ones4[3] = (short)0x3F80;

  float mrun[2] = {-__builtin_inff(), -__builtin_inff()};
  f32x4 ls[2];
  f32x4 o[2][4];
  #pragma unroll
  for (int qg = 0; qg < 2; qg++){
    ls[qg] = (f32x4){0.f,0.f,0.f,0.f};
    #pragma unroll
    for (int dc = 0; dc < 4; dc++) o[qg][dc] = (f32x4){0.f,0.f,0.f,0.f};
  }

  const int nkb = qb0/64 + 2;

#define STAGE(kb_, bf_) do { \
    gload16(Kb + kbase + (size_t)(kb_)*4096 + offK0, (unsigned short*)&k_sh[bf_][ldsA]); \
    gload16(Kb + kbase + (size_t)(kb_)*4096 + offK1, (unsigned short*)&k_sh[bf_][ldsB]); \
    gload16(Vt + vbase + (size_t)(kb_)*64   + offV0, (unsigned short*)&v_sh[bf_][ldsA]); \
    gload16(Vt + vbase + (size_t)(kb_)*64   + offV1, (unsigned short*)&v_sh[bf_][ldsB]); \
  } while(0)

  STAGE(0, 0);
  __syncthreads();

  for (int kb = 0; kb < nkb; kb++){
    const int buf = kb & 1;
    if (kb + 1 < nkb) STAGE(kb + 1, buf ^ 1);

    if (kb*64 <= qw0 + 31){
      const unsigned short* ks = k_sh[buf];
      const unsigned short* vs = v_sh[buf];
      const bool act0 = (kb*64 <= qw0 + 15);

      bf16x4 pb[2][4];
      // ---- per q-group: QK^T then softmax (keeps st live-range short) ----
      #pragma unroll
      for (int qg = 0; qg < 2; qg++){
        if (qg == 0 && !act0) continue;
        f32x4 st[4];
        __builtin_amdgcn_s_setprio(1);
        #pragma unroll
        for (int ksub = 0; ksub < 4; ksub++){
          int rowk = ksub*16 + lr;
          bf16x8 kf0 = *reinterpret_cast<const bf16x8*>(&ks[rowk*64 + ((grp ^ (rowk & 7)) * 8)]);
          bf16x8 kf1 = *reinterpret_cast<const bf16x8*>(&ks[rowk*64 + (((4 + grp) ^ (rowk & 7)) * 8)]);
          f32x4 s = (f32x4){0.f,0.f,0.f,0.f};
          s = __builtin_amdgcn_mfma_f32_16x16x32_bf16(kf0, qf[qg][0], s, 0, 0, 0);
          s = __builtin_amdgcn_mfma_f32_16x16x32_bf16(kf1, qf[qg][1], s, 0, 0, 0);
          st[ksub] = s;
        }
        __builtin_amdgcn_s_setprio(0);

        const int qgb = qw0 + qg*16;
        if (kb*64 + 63 > qgb){   // diagonal: causal mask
          #pragma unroll
          for (int ksub = 0; ksub < 4; ksub++)
            #pragma unroll
            for (int r = 0; r < 4; r++){
              int kg = kb*64 + ksub*16 + grp*4 + r;
              if (kg > qgb + lr) st[ksub][r] = -__builtin_inff();
            }
        }
        float mt = fmaxf(fmaxf(st[0][0], st[0][1]), fmaxf(st[0][2], st[0][3]));
        #pragma unroll
        for (int ksub = 1; ksub < 4; ksub++){
          mt = fmaxf(mt, fmaxf(fmaxf(st[ksub][0], st[ksub][1]),
                               fmaxf(st[ksub][2], st[ksub][3])));
        }
        mt = fmaxf(mt, __shfl_xor(mt, 16));
        mt = fmaxf(mt, __shfl_xor(mt, 32));
        const float mnew = fmaxf(mrun[qg], mt);
        const float corr = EXP2(mrun[qg] - mnew);   // exp2(-inf)=0 at first tile
        mrun[qg] = mnew;
        #pragma unroll
        for (int dc = 0; dc < 4; dc++){
          o[qg][dc][0] *= corr; o[qg][dc][1] *= corr;
          o[qg][dc][2] *= corr; o[qg][dc][3] *= corr;
        }
        ls[qg][0] *= corr;
        #pragma unroll
        for (int ksub = 0; ksub < 4; ksub++){
          float p0 = EXP2(st[ksub][0] - mnew);
          float p1 = EXP2(st[ksub][1] - mnew);
          float p2 = EXP2(st[ksub][2] - mnew);
          float p3 = EXP2(st[ksub][3] - mnew);
          union { unsigned u[2]; bf16x4 v; } pk;
          pk.u[0] = pk2bf(p0, p1);
          pk.u[1] = pk2bf(p2, p3);
          pb[qg][ksub] = pk.v;
        }
      }

      // ---- PV + l-sum on the matrix pipe ----
      __builtin_amdgcn_s_setprio(1);
      #pragma unroll
      for (int ksub = 0; ksub < 4; ksub++){
        #pragma unroll
        for (int dc = 0; dc < 4; dc++){
          int rowd = dc*16 + lr;
          int cg16 = ksub*2 + (grp >> 1);
          bf16x4 vf = *reinterpret_cast<const bf16x4*>(
              &vs[rowd*64 + ((cg16 ^ (rowd & 7)) * 8) + (grp & 1)*4]);
          if (act0) o[0][dc] = __builtin_amdgcn_mfma_f32_16x16x16bf16_1k(vf, pb[0][ksub], o[0][dc], 0, 0, 0);
          o[1][dc] = __builtin_amdgcn_mfma_f32_16x16x16bf16_1k(vf, pb[1][ksub], o[1][dc], 0, 0, 0);
        }
        if (act0) ls[0] = __builtin_amdgcn_mfma_f32_16x16x16bf16_1k(ones4, pb[0][ksub], ls[0], 0, 0, 0);
        ls[1] = __builtin_amdgcn_mfma_f32_16x16x16bf16_1k(ones4, pb[1][ksub], ls[1], 0, 0, 0);
      }
      __builtin_amdgcn_s_setprio(0);
    }
    __syncthreads();
  }
#undef STAGE

  // ---- epilogue ----
  #pragma unroll
  for (int qg = 0; qg < 2; qg++){
    float inv = 1.0f / ls[qg][0];
    int qglob = qw0 + qg*16 + lr;
    size_t ob = ((size_t)(b*SEQ + qglob))*DM + h*DKH;
    #pragma unroll
    for (int dc = 0; dc < 4; dc++){
      ushort4 pk;
      pk.x = f2bf(o[qg][dc][0]*inv);
      pk.y = f2bf(o[qg][dc][1]*inv);
      pk.z = f2bf(o[qg][dc][2]*inv);
      pk.w = f2bf(o[qg][dc][3]*inv);
      *reinterpret_cast<ushort4*>(&Oout[ob + dc*16 + grp*4]) = pk;
    }
  }
}

extern "C" void kernel_launch(void* const* d_in, const int* in_sizes, int n_in,
                              void* d_out, int out_size, void* d_ws, size_t ws_size,
                              hipStream_t stream) {
  const float* query = (const float*)d_in[0];
  const float* key   = (const float*)d_in[1];
  const float* value = (const float*)d_in[2];
  const float* Wq = (const float*)d_in[4];
  const float* bq = (const float*)d_in[5];
  const float* Wk = (const float*)d_in[6];
  const float* bk = (const float*)d_in[7];
  const float* Wv = (const float*)d_in[8];
  const float* bv = (const float*)d_in[9];
  const float* Wo = (const float*)d_in[10];
  const float* bo = (const float*)d_in[11];
  float* out = (float*)d_out;

  char* ws = (char*)d_ws;
  const size_t SZ_X = (size_t)MROWS * DM * 2;   // 16 MB
  const size_t SZ_W = (size_t)DM * DM * 2;      // 2 MB
  unsigned short* wqb = (unsigned short*)(ws + 0);
  unsigned short* wkb = (unsigned short*)(ws + SZ_W);
  unsigned short* wvb = (unsigned short*)(ws + 2*SZ_W);
  unsigned short* wob = (unsigned short*)(ws + 3*SZ_W);
  unsigned short* Qb   = (unsigned short*)(ws + 4*SZ_W);
  unsigned short* Kbuf = (unsigned short*)(ws + 4*SZ_W + SZ_X);
  unsigned short* Vt   = (unsigned short*)(ws + 4*SZ_W + 2*SZ_X);
  unsigned short* attO = (unsigned short*)(ws + 4*SZ_W + 3*SZ_X);  // total 72 MB

  ConvArgs ca;
  ca.src[0] = Wq; ca.src[1] = Wk; ca.src[2] = Wv; ca.src[3] = Wo;
  ca.dst[0] = wqb; ca.dst[1] = wkb; ca.dst[2] = wvb; ca.dst[3] = wob;
  conv_w<<<4096, 256, 0, stream>>>(ca);

  const int NBLK = (MROWS/128) * (DM/128);   // 512, XCD-swizzled in-kernel
  const float qscale = 0.125f * 1.4426950408889634f;   // 1/sqrt(dk) * log2(e)
  gemm_bt<1,1><<<NBLK, 256, 0, stream>>>(value, wvb, bv, (void*)Vt,   1.0f);
  gemm_bt<0,1><<<NBLK, 256, 0, stream>>>(query, wqb, bq, (void*)Qb,   qscale);
  gemm_bt<0,1><<<NBLK, 256, 0, stream>>>(key,   wkb, bk, (void*)Kbuf, 1.0f);

  attn_kernel<<<dim3(64, 16), 256, 0, stream>>>(Qb, Kbuf, Vt, attO);

  gemm_bt<2,0><<<NBLK, 256, 0, stream>>>(attO, wob, bo, (void*)out, 1.0f);
}